// Round 1
// baseline (745.082 us; speedup 1.0000x reference)
//
#include <hip/hip_runtime.h>
#include <math.h>

// ---------------------------------------------------------------------------
// Fused transformer block on MI355X.
// Precision: all pre-router math is fp32-equivalent (split-fp16/bf16 MFMA),
// post-routing MoE GEMMs plain bf16 MFMA.
// R5: attention restructured — S computed transposed so P exits QK^T already
// in the K=16 MFMA A-operand layout; PV chains mfma_f32_16x16x16f16 directly
// from registers (no P LDS round-trip). V pre-packed in B-operand layout
// (fp16 hi/lo interleaved) and staged via global_load_lds. LDS 52->34KB.
// R6: attention staging pipelined (T14 async-STAGE split) — next tile's K/V
// global loads issue BEFORE the current tile's compute; vmcnt drain + LDS
// writes land after the post-compute barrier. HBM latency hides under
// QK^T/softmax/PV. glds16 V replaced by reg-staged V (same LDS layout).
// s_setprio(1) around MFMA clusters (T5). Numerics bit-identical to R5.
// ---------------------------------------------------------------------------

#define B_   2
#define S_   2048
#define D_   1024
#define H_   16
#define HD_  64
#define FFN_ 2048
#define E_   8
#define CAP_ 1280
#define T_   (B_*S_)

typedef unsigned short u16;
typedef __attribute__((ext_vector_type(8))) short     short8;    // MFMA bf16x8 operand
typedef __attribute__((ext_vector_type(8))) _Float16  half8;     // MFMA f16x8 operand
typedef __attribute__((ext_vector_type(4))) _Float16  half4;     // K=16 MFMA f16x4 operand
typedef __attribute__((ext_vector_type(8))) unsigned short ushort8v;
typedef __attribute__((ext_vector_type(4))) float     f32x4;

__device__ __forceinline__ u16 f2bf(float f) {
  unsigned u = __float_as_uint(f);
  return (u16)((u + 0x7fffu + ((u >> 16) & 1u)) >> 16);   // RNE
}
__device__ __forceinline__ float bf2f(u16 h) {
  return __uint_as_float(((unsigned)h) << 16);
}
__device__ __forceinline__ u16 f2h(float f) {
  _Float16 h = (_Float16)f;
  return __builtin_bit_cast(u16, h);
}
__device__ __forceinline__ float h2f(u16 b) {
  return (float)__builtin_bit_cast(_Float16, b);
}

__device__ __forceinline__ void cstore(float* p, float v) { *p = v; }
__device__ __forceinline__ void cstore(u16* p, float v)   { *p = f2bf(v); }

// global -> LDS direct DMA, 16B per lane (lane-linear dest).
__device__ __forceinline__ void glds16(const u16* g, u16* l) {
  __builtin_amdgcn_global_load_lds(
      (const __attribute__((address_space(1))) unsigned int*)g,
      (__attribute__((address_space(3))) unsigned int*)l, 16, 0, 0);
}

// --------------------------- init: zero expert counters --------------------
__global__ void init_k(int* cnt) {
  if (threadIdx.x < 16) cnt[threadIdx.x] = 0;
}

// --------------------------- RMSNorm (fp32 in; fp32/bf16/fp16-split out) ---
__global__ __launch_bounds__(256) void rmsnorm_k(const float* __restrict__ x,
                                                 const float* __restrict__ g,
                                                 float* __restrict__ of,
                                                 u16*   __restrict__ ob,
                                                 u16*   __restrict__ ohh,
                                                 u16*   __restrict__ ohl) {
  const int t = blockIdx.x, tid = threadIdx.x;
  const float4 xv = ((const float4*)(x + (size_t)t * D_))[tid];
  float ss = xv.x*xv.x + xv.y*xv.y + xv.z*xv.z + xv.w*xv.w;
  #pragma unroll
  for (int off = 32; off; off >>= 1) ss += __shfl_down(ss, off);
  __shared__ float wsum[4];
  if ((tid & 63) == 0) wsum[tid >> 6] = ss;
  __syncthreads();
  const float tot = wsum[0] + wsum[1] + wsum[2] + wsum[3];
  const float rms = 1.0f / sqrtf(tot * (1.0f / D_) + 1e-6f);
  const float4 gv = ((const float4*)g)[tid];
  float4 o;
  o.x = gv.x * xv.x * rms;
  o.y = gv.y * xv.y * rms;
  o.z = gv.z * xv.z * rms;
  o.w = gv.w * xv.w * rms;
  if (of) ((float4*)(of + (size_t)t * D_))[tid] = o;
  if (ob) {
    ushort4 h;
    h.x = f2bf(o.x); h.y = f2bf(o.y); h.z = f2bf(o.z); h.w = f2bf(o.w);
    ((ushort4*)(ob + (size_t)t * D_))[tid] = h;
  }
  if (ohh) {
    ushort4 hh, hl;
    hh.x = f2h(o.x); hl.x = f2h(o.x - h2f(hh.x));
    hh.y = f2h(o.y); hl.y = f2h(o.y - h2f(hh.y));
    hh.z = f2h(o.z); hl.z = f2h(o.z - h2f(hh.z));
    hh.w = f2h(o.w); hl.w = f2h(o.w - h2f(hh.w));
    ((ushort4*)(ohh + (size_t)t * D_))[tid] = hh;
    ((ushort4*)(ohl + (size_t)t * D_))[tid] = hl;
  }
}

// --------------------------- split-fp16 MFMA GEMM: C = (A)(Bt)^T (+resid) --
template<bool RESID>
__global__ __launch_bounds__(256) void gemm_split(const u16* __restrict__ Ah,
                                                  const u16* __restrict__ Al,
                                                  const u16* __restrict__ Bh,
                                                  const u16* __restrict__ Bl,
                                                  const float* __restrict__ resid,
                                                  float* __restrict__ C,
                                                  int K, int lda, int ldb, int ldc) {
  __shared__ u16 AsH[128 * 32], AsL[128 * 32];
  __shared__ u16 BsH[128 * 32], BsL[128 * 32];
  const int tid = threadIdx.x;
  const int bm = blockIdx.y, bn = blockIdx.x;
  const int lane = tid & 63, wave = tid >> 6;
  const int wy = wave >> 1, wx = wave & 1;
  const int l15 = lane & 15, lq = lane >> 4;
  f32x4 acc[4][4];
  #pragma unroll
  for (int i = 0; i < 4; ++i)
    #pragma unroll
    for (int j = 0; j < 4; ++j)
      #pragma unroll
      for (int r = 0; r < 4; ++r) acc[i][j][r] = 0.0f;
  const int srow = lane >> 2, skc = (lane & 3) * 8;
  size_t ga[2], gb[2];
  int ldsoff[2];
  #pragma unroll
  for (int c = 0; c < 2; ++c) {
    const int q = wave * 2 + c;
    ga[c] = (size_t)(bm * 128 + q * 16 + srow) * lda + skc;
    gb[c] = (size_t)(bn * 128 + q * 16 + srow) * ldb + skc;
    ldsoff[c] = q * 512 + lane * 8;
  }

  for (int kt = 0; kt < K; kt += 32) {
    __syncthreads();
    #pragma unroll
    for (int c = 0; c < 2; ++c) {
      glds16(Ah + ga[c] + kt, &AsH[ldsoff[c]]);
      glds16(Al + ga[c] + kt, &AsL[ldsoff[c]]);
      glds16(Bh + gb[c] + kt, &BsH[ldsoff[c]]);
      glds16(Bl + gb[c] + kt, &BsL[ldsoff[c]]);
    }
    __syncthreads();
    half8 ah[4], al[4], bh[4], bl[4];
    #pragma unroll
    for (int i = 0; i < 4; ++i) {
      const int row = (wy * 64 + i * 16 + l15) * 32 + lq * 8;
      ah[i] = *(const half8*)&AsH[row];
      al[i] = *(const half8*)&AsL[row];
    }
    #pragma unroll
    for (int j = 0; j < 4; ++j) {
      const int row = (wx * 64 + j * 16 + l15) * 32 + lq * 8;
      bh[j] = *(const half8*)&BsH[row];
      bl[j] = *(const half8*)&BsL[row];
    }
    #pragma unroll
    for (int i = 0; i < 4; ++i)
      #pragma unroll
      for (int j = 0; j < 4; ++j) {
        acc[i][j] = __builtin_amdgcn_mfma_f32_16x16x32_f16(ah[i], bh[j], acc[i][j], 0, 0, 0);
        acc[i][j] = __builtin_amdgcn_mfma_f32_16x16x32_f16(ah[i], bl[j], acc[i][j], 0, 0, 0);
        acc[i][j] = __builtin_amdgcn_mfma_f32_16x16x32_f16(al[i], bh[j], acc[i][j], 0, 0, 0);
      }
  }
  #pragma unroll
  for (int i = 0; i < 4; ++i)
    #pragma unroll
    for (int j = 0; j < 4; ++j)
      #pragma unroll
      for (int r = 0; r < 4; ++r) {
        const int row = bm * 128 + wy * 64 + i * 16 + lq * 4 + r;
        const int col = bn * 128 + wx * 64 + j * 16 + l15;
        float v = acc[i][j][r];
        if (RESID) v += resid[(size_t)row * ldc + col];
        C[(size_t)row * ldc + col] = v;
      }
}

// --------------------------- weight transpose + fp16 split -----------------
__global__ __launch_bounds__(256) void wsplit_t_k(const float* __restrict__ src,
                                                  u16* __restrict__ dh,
                                                  u16* __restrict__ dl,
                                                  int R, int C) {
  __shared__ float tile[32][33];
  const int tid = threadIdx.x;
  const int r0 = blockIdx.y * 32, c0 = blockIdx.x * 32;
  const int tx = tid & 31, ty = tid >> 5;
  #pragma unroll
  for (int i = 0; i < 4; ++i)
    tile[ty + i * 8][tx] = src[(size_t)(r0 + ty + i * 8) * C + c0 + tx];
  __syncthreads();
  #pragma unroll
  for (int i = 0; i < 4; ++i) {
    const float v = tile[tx][ty + i * 8];
    const u16 hh = f2h(v);
    const size_t o = (size_t)(c0 + ty + i * 8) * R + r0 + tx;
    dh[o] = hh;
    dl[o] = f2h(v - h2f(hh));
  }
}

// --------------------------- RoPE + split q,k -> bf16 hi/lo ----------------
__global__ __launch_bounds__(256) void ropesplit_k(const float* __restrict__ qkv,
                                                   u16* __restrict__ qhi, u16* __restrict__ qlo,
                                                   u16* __restrict__ khi, u16* __restrict__ klo) {
  const int i = blockIdx.x * 256 + threadIdx.x;   // over T_*H_*32
  const int j = i & 31;
  const int h = (i >> 5) & 15;
  const int t = i >> 9;
  const int s = t & (S_ - 1);
  const int b = t >> 11;
  const int bh = b * 16 + h;
  const float theta = (float)pow(10000.0, -(double)j / 32.0);
  const float fr = (float)s * theta;
  const float c = cosf(fr), sn = sinf(fr);
  const float2 q = *(const float2*)(qkv + (size_t)t * 3072 + h * 64 + 2 * j);
  const float2 k = *(const float2*)(qkv + (size_t)t * 3072 + 1024 + h * 64 + 2 * j);
  const float q0 = (q.x * c - q.y * sn) * 0.125f;
  const float q1 = (q.x * sn + q.y * c) * 0.125f;
  const float k0 = k.x * c - k.y * sn;
  const float k1 = k.x * sn + k.y * c;
  const size_t o = ((size_t)bh * S_ + s) * 32 + j;   // uint (2xu16) index
  const u16 qh0 = f2bf(q0), qh1 = f2bf(q1);
  const u16 kh0 = f2bf(k0), kh1 = f2bf(k1);
  ((unsigned*)qhi)[o] = (unsigned)qh0 | ((unsigned)qh1 << 16);
  ((unsigned*)khi)[o] = (unsigned)kh0 | ((unsigned)kh1 << 16);
  const u16 ql0 = f2bf(q0 - bf2f(qh0)), ql1 = f2bf(q1 - bf2f(qh1));
  const u16 kl0 = f2bf(k0 - bf2f(kh0)), kl1 = f2bf(k1 - bf2f(kh1));
  ((unsigned*)qlo)[o] = (unsigned)ql0 | ((unsigned)ql1 << 16);
  ((unsigned*)klo)[o] = (unsigned)kl0 | ((unsigned)kl1 << 16);
}

// --------------------------- V pack: fp16 hi/lo in K=16 B-operand layout ---
// Per (bh, key-tile kt): group g=(kc*4+n)*64+lane holds 8 u16:
// [ V[kt*64+kc*16+(lane>>4)*4+j][n*16+(lane&15)] hi j=0..3 | lo j=0..3 ]
__global__ __launch_bounds__(256) void vpack_k(const float* __restrict__ qkv,
                                               u16* __restrict__ vpk) {
  const int kt = blockIdx.x, bh = blockIdx.y;
  const int b = bh >> 4, h = bh & 15;
  const int tid = threadIdx.x;
  u16* dst = vpk + (size_t)(bh * 32 + kt) * 8192;
  #pragma unroll
  for (int i = 0; i < 4; ++i) {
    const int g = i * 256 + tid;               // 0..1023
    const int lane = g & 63, n = (g >> 6) & 3, kc = g >> 8;
    const int lq = lane >> 4, l15 = lane & 15;
    const int key = kt * 64 + kc * 16 + lq * 4;
    const int d = n * 16 + l15;
    u16 out[8];
    #pragma unroll
    for (int j = 0; j < 4; ++j) {
      const float v = qkv[(size_t)(b * S_ + key + j) * 3072 + 2048 + h * 64 + d];
      const u16 hh = f2h(v);
      out[j] = hh;
      out[4 + j] = f2h(v - h2f(hh));
    }
    *(ushort8v*)(dst + g * 8) = *(ushort8v*)out;
  }
}

// --------------------------- MFMA flash attention (split-K, chained PV) ----
// S computed transposed: mfma(A=K, B=Q) -> C-layout query=l15, key=lq*4+r,
// which IS the K=16 A-operand layout. PV chains mfma_f32_16x16x16f16 from
// registers (split-fp16 P and V). No P LDS round-trip.
// R6: T14 async-STAGE — next tile's K/V global loads are issued before the
// current tile's compute; LDS writes happen after the post-compute barrier.
__global__ __launch_bounds__(256, 4) void attn_mfma_k(const u16* __restrict__ qhi,
                                                      const u16* __restrict__ qlo,
                                                      const u16* __restrict__ khi,
                                                      const u16* __restrict__ klo,
                                                      const u16* __restrict__ vpk,
                                                      u16* __restrict__ ahh,
                                                      u16* __restrict__ ahl,
                                                      float* __restrict__ PO,
                                                      float* __restrict__ Pm,
                                                      float* __restrict__ Pl2) {
  __shared__ u16 Kh[64 * 68], Kl[64 * 68];   // [key][dim], padded (0-conflict)
  __shared__ u16 Vp[8192];                   // packed fp16 hi/lo B-operand
  const int tid = threadIdx.x, lane = tid & 63, wave = tid >> 6;
  const int bi = blockIdx.x;
  int qt, k0, k1, chunk;
  bool partial;
  if (bi < 32) {
    qt = 31 - (bi >> 1); chunk = bi & 1;
    const int nk = qt + 1, cut = nk >> 1;
    k0 = chunk ? cut : 0;
    k1 = chunk ? nk : cut;
    partial = true;
  } else {
    qt = 47 - bi; chunk = 0; k0 = 0; k1 = qt + 1; partial = false;
  }
  const int bh = blockIdx.y;
  const int l15 = lane & 15, lq = lane >> 4;
  const size_t hb = (size_t)bh * S_ * 64;
  // Q as B-operand: lane n=l15 -> query, k=lq*8+j (same per-lane data as A).
  const int qrow = qt * 64 + wave * 16 + l15;
  short8 qh[2], ql[2];
  qh[0] = *(const short8*)(qhi + hb + (size_t)qrow * 64 + lq * 8);
  qh[1] = *(const short8*)(qhi + hb + (size_t)qrow * 64 + 32 + lq * 8);
  ql[0] = *(const short8*)(qlo + hb + (size_t)qrow * 64 + lq * 8);
  ql[1] = *(const short8*)(qlo + hb + (size_t)qrow * 64 + 32 + lq * 8);
  f32x4 O[4];
  #pragma unroll
  for (int n = 0; n < 4; ++n)
    #pragma unroll
    for (int r = 0; r < 4; ++r) O[n][r] = 0.0f;
  float m_i = -__builtin_inff(), l_i = 0.0f;  // for query = wave*16 + l15

  // Per-thread staging addresses (tile-invariant parts).
  const int sidx0 = tid,       srow0 = sidx0 >> 3, sc80 = (sidx0 & 7) * 8;
  const int sidx1 = 256 + tid, srow1 = sidx1 >> 3, sc81 = (sidx1 & 7) * 8;
  const int vlds = wave * 2048 + lane * 8;
  ushort8v kregH[2], kregL[2], vreg[4];

  // Issue next-tile global loads (stay in flight across compute).
  auto issue_loads = [&](int kt) {
    const size_t koff0 = hb + (size_t)(kt * 64 + srow0) * 64 + sc80;
    const size_t koff1 = hb + (size_t)(kt * 64 + srow1) * 64 + sc81;
    kregH[0] = *(const ushort8v*)(khi + koff0);
    kregL[0] = *(const ushort8v*)(klo + koff0);
    kregH[1] = *(const ushort8v*)(khi + koff1);
    kregL[1] = *(const ushort8v*)(klo + koff1);
    const u16* vg = vpk + (size_t)(bh * 32 + kt) * 8192 + vlds;
    #pragma unroll
    for (int c = 0; c < 4; ++c)
      vreg[c] = *(const ushort8v*)(vg + c * 512);
  };
  // Drain + write staged regs to LDS (lane-linear V; padded K rows).
  auto write_lds = [&]() {
    *(ushort8v*)&Kh[srow0 * 68 + sc80] = kregH[0];
    *(ushort8v*)&Kl[srow0 * 68 + sc80] = kregL[0];
    *(ushort8v*)&Kh[srow1 * 68 + sc81] = kregH[1];
    *(ushort8v*)&Kl[srow1 * 68 + sc81] = kregL[1];
    #pragma unroll
    for (int c = 0; c < 4; ++c)
      *(ushort8v*)&Vp[vlds + c * 512] = vreg[c];
  };

  // Prologue: stage first tile.
  issue_loads(k0);
  write_lds();
  __syncthreads();

  for (int kt = k0; kt < k1; ++kt) {
    const bool pf = (kt + 1 < k1);
    if (pf) issue_loads(kt + 1);   // in flight under compute (T14)
    // ---- S^T = K Q^T (3-product split): sc[kc][r]: key=kc*16+lq*4+r,
    //      query=wave*16+l15 ----
    f32x4 sc[4];
    #pragma unroll
    for (int kc = 0; kc < 4; ++kc)
      #pragma unroll
      for (int r = 0; r < 4; ++r) sc[kc][r] = 0.0f;
    __builtin_amdgcn_s_setprio(1);
    #pragma unroll
    for (int kc = 0; kc < 4; ++kc) {
      const int krow = (kc * 16 + l15) * 68 + lq * 8;
      const short8 kb0 = *(const short8*)&Kh[krow];
      const short8 kb1 = *(const short8*)&Kh[krow + 32];
      const short8 kl0 = *(const short8*)&Kl[krow];
      const short8 kl1 = *(const short8*)&Kl[krow + 32];
      sc[kc] = __builtin_amdgcn_mfma_f32_16x16x32_bf16(kb0, qh[0], sc[kc], 0, 0, 0);
      sc[kc] = __builtin_amdgcn_mfma_f32_16x16x32_bf16(kb1, qh[1], sc[kc], 0, 0, 0);
      sc[kc] = __builtin_amdgcn_mfma_f32_16x16x32_bf16(kb0, ql[0], sc[kc], 0, 0, 0);
      sc[kc] = __builtin_amdgcn_mfma_f32_16x16x32_bf16(kb1, ql[1], sc[kc], 0, 0, 0);
      sc[kc] = __builtin_amdgcn_mfma_f32_16x16x32_bf16(kl0, qh[0], sc[kc], 0, 0, 0);
      sc[kc] = __builtin_amdgcn_mfma_f32_16x16x32_bf16(kl1, qh[1], sc[kc], 0, 0, 0);
    }
    __builtin_amdgcn_s_setprio(0);
    // ---- causal mask on the diagonal tile ----
    if (kt == qt) {
      #pragma unroll
      for (int kc = 0; kc < 4; ++kc)
        #pragma unroll
        for (int r = 0; r < 4; ++r)
          if (kc * 16 + lq * 4 + r > wave * 16 + l15) sc[kc][r] = -__builtin_inff();
    }
    // ---- online softmax: row (query) state is per-lane scalar ----
    float mx = -__builtin_inff();
    #pragma unroll
    for (int kc = 0; kc < 4; ++kc)
      #pragma unroll
      for (int r = 0; r < 4; ++r) mx = fmaxf(mx, sc[kc][r]);
    mx = fmaxf(mx, __shfl_xor(mx, 16));
    mx = fmaxf(mx, __shfl_xor(mx, 32));
    const float mn = fmaxf(m_i, mx);
    const float alpha = __expf(m_i - mn);
    m_i = mn;
    f32x4 p[4];
    float rs = 0.0f;
    #pragma unroll
    for (int kc = 0; kc < 4; ++kc)
      #pragma unroll
      for (int r = 0; r < 4; ++r) { p[kc][r] = __expf(sc[kc][r] - m_i); rs += p[kc][r]; }
    rs += __shfl_xor(rs, 16);
    rs += __shfl_xor(rs, 32);
    l_i = l_i * alpha + rs;
    // rescale O: O[n][r] belongs to query lq*4+r -> fetch that query's alpha
    #pragma unroll
    for (int r = 0; r < 4; ++r) {
      const float alr = __shfl(alpha, lq * 4 + r);
      #pragma unroll
      for (int n = 0; n < 4; ++n) O[n][r] *= alr;
    }
    // ---- P -> split-fp16 in registers (K=16 A-operand layout) ----
    half4 ph[4], pl[4];
    #pragma unroll
    for (int kc = 0; kc < 4; ++kc)
      #pragma unroll
      for (int r = 0; r < 4; ++r) {
        const _Float16 hi = (_Float16)p[kc][r];
        ph[kc][r] = hi;
        pl[kc][r] = (_Float16)(p[kc][r] - (float)hi);
      }
    // ---- O += P V, chained K=16 MFMAs (hh, hl, lh) ----
    __builtin_amdgcn_s_setprio(1);
    #pragma unroll
    for (int n = 0; n < 4; ++n)
      #pragma unroll
      for (int kc = 0; kc < 4; ++kc) {
        const int g = ((kc * 4 + n) * 64 + lane) * 8;
        const half4 vh = *(const half4*)&Vp[g];
        const half4 vl = *(const half4*)&Vp[g + 4];
        O[n] = __builtin_amdgcn_mfma_f32_16x16x16f16(ph[kc], vh, O[n], 0, 0, 0);
        O[n] = __builtin_amdgcn_mfma_f32_16x16x16f16(ph[kc], vl, O[n], 0, 0, 0);
        O[n] = __builtin_amdgcn_mfma_f32_16x16x16f16(pl[kc], vh, O[n], 0, 0, 0);
      }
    __builtin_amdgcn_s_setprio(0);
    // All waves done reading tile kt; overwrite LDS with prefetched tile.
    __syncthreads();
    if (pf) write_lds();
    __syncthreads();
  }
  const int b = bh >> 4, h = bh & 15;
  if (!partial) {
    #pragma unroll
    for (int r = 0; r < 4; ++r) {
      const float lr = __shfl(l_i, lq * 4 + r);
      const float inv = 1.0f / lr;
      const int row = qt * 64 + wave * 16 + lq * 4 + r;
      const size_t base = (size_t)(b * S_ + row) * D_ + h * 64 + l15;
      #pragma unroll
      for (int n = 0; n < 4; ++n) {
        const float o = O[n][r] * inv;
        const u16 hh = f2h(o);
        ahh[base + n * 16] = hh;
        ahl[base + n * 16] = f2h(o - h2f(hh));
      }
    }
  } else {
    // unnormalized partials; rows are >= 1024 since qt >= 16
    #pragma unroll
    for (int r = 0; r < 4; ++r) {
      const int prow = qt * 64 + wave * 16 + lq * 4 + r - 1024;
      const size_t idx = (size_t)(chunk * 32 + bh) * 1024 + prow;
      float* po = PO + idx * 64;
      #pragma unroll
      for (int n = 0; n < 4; ++n) po[n * 16 + l15] = O[n][r];
    }
    if (lq == 0) {   // lane holds m/l for query wave*16 + l15
      const int prow = qt * 64 + wave * 16 + l15 - 1024;
      const size_t idx = (size_t)(chunk * 32 + bh) * 1024 + prow;
      Pm[idx] = m_i; Pl2[idx] = l_i;
    }
  }
}

// --------------------------- combine split-K attention partials ------------
__global__ __launch_bounds__(256) void attn_combine_k(const float* __restrict__ PO,
                                                      const float* __restrict__ Pm,
                                                      const float* __restrict__ Pl2,
                                                      u16* __restrict__ ahh,
                                                      u16* __restrict__ ahl) {
  const int tid = threadIdx.x;
  const int bh = blockIdx.y, b = bh >> 4, h = bh & 15;
  const int prow = blockIdx.x * 64 + (tid >> 2);
  const int d0 = (tid & 3) * 16;
  const size_t i0 = (size_t)bh * 1024 + prow;
  const size_t i1 = (size_t)(32 + bh) * 1024 + prow;
  const float m0 = Pm[i0], m1 = Pm[i1];
  const float M = fmaxf(m0, m1);
  const float w0 = __expf(m0 - M), w1 = __expf(m1 - M);
  const float inv = 1.0f / (w0 * Pl2[i0] + w1 * Pl2[i1]);
  const int row = 1024 + prow;
  const size_t ob = (size_t)(b * S_ + row) * D_ + h * 64 + d0;
  #pragma unroll
  for (int q4 = 0; q4 < 4; ++q4) {
    const float4 o0 = *(const float4*)(PO + i0 * 64 + d0 + q4 * 4);
    const float4 o1 = *(const float4*)(PO + i1 * 64 + d0 + q4 * 4);
    float v[4];
    v[0] = (w0 * o0.x + w1 * o1.x) * inv;
    v[1] = (w0 * o0.y + w1 * o1.y) * inv;
    v[2] = (w0 * o0.z + w1 * o1.z) * inv;
    v[3] = (w0 * o0.w + w1 * o1.w) * inv;
    ushort4 hh, hl;
    u16* ph = (u16*)&hh;
    u16* pl = (u16*)&hl;
    #pragma unroll
    for (int z = 0; z < 4; ++z) {
      ph[z] = f2h(v[z]);
      pl[z] = f2h(v[z] - h2f(ph[z]));
    }
    *(ushort4*)(ahh + ob + q4 * 4) = hh;
    *(ushort4*)(ahl + ob + q4 * 4) = hl;
  }
}

// --------------------------- router: logits + top2 + capacity assign -------
__global__ __launch_bounds__(256) void router_k(const float* __restrict__ y2,
                                                const float* __restrict__ wr,
                                                int*   __restrict__ cnt,
                                                int*   __restrict__ tok_e,
                                                float* __restrict__ tok_g,
                                                int*   __restrict__ tok_p,
                                                int*   __restrict__ etok) {
  const int wave = threadIdx.x >> 6, lane = threadIdx.x & 63;
  const int t = blockIdx.x * 4 + wave;
  const float* xr = y2 + (size_t)t * D_;
  float acc[8];
  #pragma unroll
  for (int e = 0; e < 8; ++e) acc[e] = 0.0f;
  for (int c = 0; c < 16; ++c) {
    const float xv = xr[c * 64 + lane];
    const float* w = wr + (size_t)(c * 64 + lane) * 8;
    #pragma unroll
    for (int e = 0; e < 8; ++e) acc[e] = fmaf(xv, w[e], acc[e]);
  }
  #pragma unroll
  for (int off = 32; off; off >>= 1)
    #pragma unroll
    for (int e = 0; e < 8; ++e) acc[e] += __shfl_down(acc[e], off);
  if (lane == 0) {
    float mx = acc[0];
    #pragma unroll
    for (int e = 1; e < 8; ++e) mx = fmaxf(mx, acc[e]);
    float ex[8], sum = 0.0f;
    #pragma unroll
    for (int e = 0; e < 8; ++e) { ex[e] = expf(acc[e] - mx); sum += ex[e]; }
    int e1 = 0;
    #pragma unroll
    for (int e = 1; e < 8; ++e) if (acc[e] > acc[e1]) e1 = e;
    int e2 = (e1 == 0) ? 1 : 0;
    #pragma unroll
    for (int e = 0; e < 8; ++e) if (e != e1 && acc[e] > acc[e2]) e2 = e;
    const float g1v = ex[e1] / sum, g2v = ex[e2] / sum;
    int p1 = atomicAdd(&cnt[e1], 1);
    int p2 = atomicAdd(&cnt[e2], 1);
    if (p1 < CAP_) etok[e1 * CAP_ + p1] = t; else p1 = -1;
    if (p2 < CAP_) etok[e2 * CAP_ + p2] = t; else p2 = -1;
    tok_e[2*t] = e1;   tok_e[2*t+1] = e2;
    tok_g[2*t] = g1v;  tok_g[2*t+1] = g2v;
    tok_p[2*t] = p1;   tok_p[2*t+1] = p2;
  }
}

// --------------------------- gather tokens per expert (bf16) ---------------
__global__ __launch_bounds__(256) void gather_k(const u16* __restrict__ y2b,
                                                const int* __restrict__ etok,
                                                const int* __restrict__ cnt,
                                                u16* __restrict__ xe) {
  const int e = blockIdx.y, pos = blockIdx.x, tid = threadIdx.x;
  const int n = min(cnt[e], CAP_);
  ushort4* dst = (ushort4*)(xe + (size_t)(e * CAP_ + pos) * D_) + tid;
  if (pos < n) {
    const int t = etok[e * CAP_ + pos];
    *dst = ((const ushort4*)(y2b + (size_t)t * D_))[tid];
  } else {
    *dst = make_ushort4(0, 0, 0, 0);
  }
}

// --------------------------- bf16 MFMA GEMM: C = A * Bt^T ------------------
template<typename OT, bool RELU>
__global__ __launch_bounds__(256) void gemm_bt(const u16* __restrict__ A,
                                               const u16* __restrict__ Bt,
                                               OT* __restrict__ C,
                                               int M, int N, int K,
                                               int lda, int ldb, int ldc,
                                               long sAz, long sBz, long sCz) {
  __shared__ u16 As[128 * 32];
  __shared__ u16 Bs[128 * 32];
  const int tid = threadIdx.x;
  A  += (size_t)blockIdx.z * sAz;
  Bt += (size_t)blockIdx.z * sBz;
  C  += (size_t)blockIdx.z * sCz;
  const int bm = blockIdx.y, bn = blockIdx.x;
  const int lane = tid & 63, wave = tid >> 6;
  const int wy = wave >> 1, wx = wave & 1;
  const int l15 = lane & 15, lq = lane >> 4;
  f32x4 acc[4][4];
  #pragma unroll
  for (int i = 0; i < 4; ++i)
    #pragma unroll
    for (int j = 0; j < 4; ++j)
      #pragma unroll
      for (int r = 0; r < 4; ++r) acc[i][j][r] = 0.0f;
  const int srow = lane >> 2, skc = (lane & 3) * 8;
  size_t ga[2], gb[2];
  int ldsoff[2];
  #pragma unroll
  for (int c = 0; c < 2; ++c) {
    const int q = wave * 2 + c;
    ga[c] = (size_t)(bm * 128 + q * 16 + srow) * lda + skc;
    gb[c] = (size_t)(bn * 128 + q * 16 + srow) * ldb + skc;
    ldsoff[c] = q * 512 + lane * 8;
  }

  for (int kt = 0; kt < K; kt += 32) {
    __syncthreads();
    #pragma unroll
    for (int c = 0; c < 2; ++c) {
      glds16(A  + ga[c] + kt, &As[ldsoff[c]]);
      glds16(Bt + gb[c] + kt, &Bs[ldsoff[c]]);
    }
    __syncthreads();
    short8 a[4], b[4];
    #pragma unroll
    for (int i = 0; i < 4; ++i)
      a[i] = *(const short8*)&As[(wy * 64 + i * 16 + l15) * 32 + lq * 8];
    #pragma unroll
    for (int j = 0; j < 4; ++j)
      b[j] = *(const short8*)&Bs[(wx * 64 + j * 16 + l15) * 32 + lq * 8];
    #pragma unroll
    for (int i = 0; i < 4; ++i)
      #pragma unroll
      for (int j = 0; j < 4; ++j)
        acc[i][j] = __builtin_amdgcn_mfma_f32_16x16x32_bf16(a[i], b[j], acc[i][j], 0, 0, 0);
  }
  #pragma unroll
  for (int i = 0; i < 4; ++i)
    #pragma unroll
    for (int j = 0; j < 4; ++j)
      #pragma unroll
      for (int r = 0; r < 4; ++r) {
        const int row = bm * 128 + wy * 64 + i * 16 + lq * 4 + r;
        const int col = bn * 128 + wx * 64 + j * 16 + l15;
        float v = acc[i][j][r];
        if (RELU) v = fmaxf(v, 0.0f);
        cstore(C + (size_t)row * ldc + col, v);
      }
}

// --------------------------- weight transpose fp32 -> bf16^T ---------------
__global__ __launch_bounds__(256) void transpose_bf_k(const float* __restrict__ src,
                                                      u16* __restrict__ dst,
                                                      int R, int C) {
  __shared__ float tile[32][33];
  const int tid = threadIdx.x;
  const size_t zoff = (size_t)blockIdx.z * R * C;
  const int r0 = blockIdx.y * 32, c0 = blockIdx.x * 32;
  const int tx = tid & 31, ty = tid >> 5;
  #pragma unroll
  for (int i = 0; i < 4; ++i)
    tile[ty + i * 8][tx] = src[zoff + (size_t)(r0 + ty + i * 8) * C + c0 + tx];
  __syncthreads();
  #pragma unroll
  for (int i = 0; i < 4; ++i)
    dst[zoff + (size_t)(c0 + ty + i * 8) * R + r0 + tx] = f2bf(tile[tx][ty + i * 8]);
}

// --------------------------- final combine ---------------------------------
__global__ __launch_bounds__(256) void combine_k(const float* __restrict__ x2,
                                                 const float* __restrict__ ye,
                                                 const int*   __restrict__ tok_e,
                                                 const float* __restrict__ tok_g,
                                                 const int*   __restrict__ tok_p,
                                                 float* __restrict__ out) {
  const int t = blockIdx.x, tid = threadIdx.x;
  float4 v = ((const float4*)(x2 + (size_t)t * D_))[tid];
  #pragma unroll
  for (int r = 0; r < 2; ++r) {
    const int p = tok_p[2 * t + r];
    if (p >= 0) {
      const int e = tok_e[2 * t + r];
      const float g = tok_g[2 * t + r];
      const float4 y = ((const float4*)(ye + (size_t)(e * CAP_ + p) * D_))[tid];
      v.x = fmaf(g, y.x, v.x);
      v.y = fmaf(g, y.y, v.y);
      v.z = fmaf(g, y.z, v.z);
      v.w = fmaf(g, y.w, v.w);
    }
  }
  ((float4*)(out + (size_t)t * D_))[tid] = v;
}

// ---------------------------------------------------------------------------
extern "C" void kernel_launch(void* const* d_in, const int* in_sizes, int n_in,
                              void* d_out, int out_size, void* d_ws, size_t ws_size,
                              hipStream_t stream) {
  const float* x    = (const float*)d_in[0];
  const float* g1   = (const float*)d_in[1];
  const float* wqkv = (const float*)d_in[2];
  const float* wo   = (const float*)d_in[3];
  const float* g2   = (const float*)d_in[4];
  const float* wr   = (const float*)d_in[5];
  const float* w1   = (const float*)d_in[6];
  const float* w2   = (const float*)d_in[7];
  float* out = (float*)d_out;
  char* ws = (char*)d_ws;
  const size_t MB = 1ull << 20;

  // Phase-aliased workspace layout (~233 MB):
  u16*   y1hh  = (u16*)  (ws + 0);          // 8MB  fp16-hi of rmsnorm1 out; reused as qhi
  u16*   y1hl  = (u16*)  (ws + 8 * MB);     // 8MB  fp16-lo; reused as qlo
  u16*   ahh   = (u16*)  (ws + 16 * MB);    // 8MB  attn out fp16-hi
  u16*   ahl   = (u16*)  (ws + 24 * MB);    // 8MB  attn out fp16-lo
  u16*   hbf   = (u16*)  (ws + 0);          // 40MB MoE hidden (aliases the above)
  float* qkv   = (float*)(ws + 40 * MB);    // 48MB, dead after rope/v pack
  float* PO    = (float*)(ws + 40 * MB);    // 16.8MB attn split-K partials (after vpack)
  float* Pm    = (float*)(ws + 58 * MB);    // 0.26MB
  float* Pl2   = (float*)(ws + 59 * MB);    // 0.26MB
  u16*   xe    = (u16*)  (ws + 40 * MB);    // 20MB, aliases qkv/PO (MoE time)
  float* x2    = (float*)(ws + 88 * MB);    // 16MB
  float* y2    = (float*)(ws + 104 * MB);   // 16MB (fp32 for router!)
  u16*   y2b   = (u16*)  (ws + 120 * MB);   // 8MB
  u16*   w1t   = (u16*)  (ws + 128 * MB);   // 32MB  [E][FFN][D] bf16
  u16*   w2t   = (u16*)  (ws + 160 * MB);   // 32MB  [E][D][FFN] bf16
  float* ye    = (float*)(ws + 192 * MB);   // 40MB (MoE time)
  u16*   wqh   = (u16*)  (ws + 192 * MB);   // 6MB  w_qkv^T fp16-hi (dead before rope)
  u16*   wql   = (u16*)  (ws + 198 * MB);   // 6MB  fp16-lo
  u16*   khi   = (u16*)  (ws + 192 * MB);   // 8MB  (after QKV gemm)
  u16*   klo   = (u16*)  (ws + 200 * MB);   // 8MB
  u16*   vpk   = (u16*)  (ws + 208 * MB);   // 16MB packed V fp16 hi/lo
  u16*   woh   = (u16*)  (ws + 224 * MB);   // 2MB  w_o^T fp16-hi (dead before MoE ye)
  u16*   wol   = (u16*)  (ws + 226 * MB);   // 2MB
  int*   cnt   = (int*)  (ws + 232 * MB);
  int*   tok_e = cnt + 16;                  // 2*T
  float* tok_g = (float*)(tok_e + 2 * T_);  // 2*T
  int*   tok_p = (int*)  (tok_g + 2 * T_);  // 2*T
  int*   etok  = tok_p + 2 * T_;            // E*CAP

  init_k<<<1, 64, 0, stream>>>(cnt);
  transpose_bf_k<<<dim3(FFN_/32, D_/32, E_), 256, 0, stream>>>(w1, w1t, D_, FFN_);
  transpose_bf_k<<<dim3(D_/32, FFN_/32, E_), 256, 0, stream>>>(w2, w2t, FFN_, D_);
  // w_qkv (Dx3D) -> [3D][D] fp16 hi/lo; w_o (DxD) -> [D][D] fp16 hi/lo
  wsplit_t_k<<<dim3(3*D_/32, D_/32), 256, 0, stream>>>(wqkv, wqh, wql, D_, 3*D_);
  wsplit_t_k<<<dim3(D_/32, D_/32), 256, 0, stream>>>(wo, woh, wol, D_, D_);

  // x -> rmsnorm -> y1 (fp16 hi/lo only)
  rmsnorm_k<<<T_, 256, 0, stream>>>(x, g1, (float*)nullptr, (u16*)nullptr, y1hh, y1hl);
  // qkv = y1 @ w_qkv via split-fp16 MFMA (fp32 out)
  gemm_split<false><<<dim3(3 * D_ / 128, T_ / 128), 256, 0, stream>>>(
      y1hh, y1hl, wqh, wql, nullptr, qkv, D_, D_, D_, 3 * D_);
  // RoPE + split q,k (q pre-scaled by 1/8); y1hh/y1hl are dead -> reuse as qhi/qlo
  ropesplit_k<<<T_ * H_ * 32 / 256, 256, 0, stream>>>(qkv, y1hh, y1hl, khi, klo);
  // V -> packed fp16 hi/lo B-operand layout
  vpack_k<<<dim3(S_ / 64, B_ * H_), 256, 0, stream>>>(qkv, vpk);
  // MFMA flash attention (split-K, chained PV, T14-pipelined staging)
  attn_mfma_k<<<dim3(48, B_ * H_), 256, 0, stream>>>(
      y1hh, y1hl, khi, klo, vpk, ahh, ahl, PO, Pm, Pl2);
  attn_combine_k<<<dim3(16, B_ * H_), 256, 0, stream>>>(PO, Pm, Pl2, ahh, ahl);
  // x2 = attn @ w_o + x via split-fp16 MFMA
  gemm_split<true><<<dim3(D_ / 128, T_ / 128), 256, 0, stream>>>(
      ahh, ahl, woh, wol, x, x2, D_, D_, D_, D_);
  // x2 -> rmsnorm -> y2 (fp32) + y2b (bf16)
  rmsnorm_k<<<T_, 256, 0, stream>>>(x2, g2, y2, y2b, (u16*)nullptr, (u16*)nullptr);
  // router (fp32 logits, top-2, capacity assignment)
  router_k<<<T_ / 4, 256, 0, stream>>>(y2, wr, cnt, tok_e, tok_g, tok_p, etok);
  // gather per-expert token rows (bf16)
  gather_k<<<dim3(CAP_, E_), 256, 0, stream>>>(y2b, etok, cnt, xe);
  // h = relu(xe @ w1) (bf16 out), batched over experts
  gemm_bt<u16, true><<<dim3(FFN_/128, CAP_/128, E_), 256, 0, stream>>>(
      xe, w1t, hbf, CAP_, FFN_, D_, D_, D_, FFN_,
      (long)CAP_ * D_, (long)FFN_ * D_, (long)CAP_ * FFN_);
  // ye = h @ w2 (fp32 out)
  gemm_bt<float, false><<<dim3(D_/128, CAP_/128, E_), 256, 0, stream>>>(
      hbf, w2t, ye, CAP_, D_, FFN_, FFN_, FFN_, D_,
      (long)CAP_ * FFN_, (long)D_ * FFN_, (long)CAP_ * D_);
  // out = x2 + sum_r gate_r * ye[...]
  combine_k<<<T_, 256, 0, stream>>>(x2, ye, tok_e, tok_g, tok_p, out);
}

// Round 2
// 720.819 us; speedup vs baseline: 1.0337x; 1.0337x over previous
//
#include <hip/hip_runtime.h>
#include <math.h>

// ---------------------------------------------------------------------------
// Fused transformer block on MI355X.
// Precision: all pre-router math is fp32-equivalent (split-fp16/bf16 MFMA),
// post-routing MoE GEMMs plain bf16 MFMA.
// R5: attention restructured — S computed transposed so P exits QK^T already
// in the K=16 MFMA A-operand layout; PV chains mfma_f32_16x16x16f16 directly
// from registers (no P LDS round-trip).
// R6: T14 async-STAGE staging pipeline + s_setprio around MFMA clusters.
// R7: attention split-K rebalanced — every qt chunked into <=8-tile chunks
// (grid 1536->2560 blocks, max block work 16->8 tiles) with generalized
// 2-4-chunk combine; K-tile LDS pad replaced by XOR swizzle so LDS drops
// 33792->32768 B (5 blocks/CU). MoE gemm_bt double-buffered (T3-min):
// stage tile t+1 before compute of t, one barrier per K-step.
// ---------------------------------------------------------------------------

#define B_   2
#define S_   2048
#define D_   1024
#define H_   16
#define HD_  64
#define FFN_ 2048
#define E_   8
#define CAP_ 1280
#define T_   (B_*S_)
#define NSLOT_ 72   // partial-chunk slots per (b,h): qt8-15:2ea, 16-23:3ea, 24-31:4ea

typedef unsigned short u16;
typedef __attribute__((ext_vector_type(8))) short     short8;    // MFMA bf16x8 operand
typedef __attribute__((ext_vector_type(8))) _Float16  half8;     // MFMA f16x8 operand
typedef __attribute__((ext_vector_type(4))) _Float16  half4;     // K=16 MFMA f16x4 operand
typedef __attribute__((ext_vector_type(8))) unsigned short ushort8v;
typedef __attribute__((ext_vector_type(4))) float     f32x4;

__device__ __forceinline__ u16 f2bf(float f) {
  unsigned u = __float_as_uint(f);
  return (u16)((u + 0x7fffu + ((u >> 16) & 1u)) >> 16);   // RNE
}
__device__ __forceinline__ float bf2f(u16 h) {
  return __uint_as_float(((unsigned)h) << 16);
}
__device__ __forceinline__ u16 f2h(float f) {
  _Float16 h = (_Float16)f;
  return __builtin_bit_cast(u16, h);
}
__device__ __forceinline__ float h2f(u16 b) {
  return (float)__builtin_bit_cast(_Float16, b);
}

__device__ __forceinline__ void cstore(float* p, float v) { *p = v; }
__device__ __forceinline__ void cstore(u16* p, float v)   { *p = f2bf(v); }

// global -> LDS direct DMA, 16B per lane (lane-linear dest).
__device__ __forceinline__ void glds16(const u16* g, u16* l) {
  __builtin_amdgcn_global_load_lds(
      (const __attribute__((address_space(1))) unsigned int*)g,
      (__attribute__((address_space(3))) unsigned int*)l, 16, 0, 0);
}

// --------------------------- init: zero expert counters --------------------
__global__ void init_k(int* cnt) {
  if (threadIdx.x < 16) cnt[threadIdx.x] = 0;
}

// --------------------------- RMSNorm (fp32 in; fp32/bf16/fp16-split out) ---
__global__ __launch_bounds__(256) void rmsnorm_k(const float* __restrict__ x,
                                                 const float* __restrict__ g,
                                                 float* __restrict__ of,
                                                 u16*   __restrict__ ob,
                                                 u16*   __restrict__ ohh,
                                                 u16*   __restrict__ ohl) {
  const int t = blockIdx.x, tid = threadIdx.x;
  const float4 xv = ((const float4*)(x + (size_t)t * D_))[tid];
  float ss = xv.x*xv.x + xv.y*xv.y + xv.z*xv.z + xv.w*xv.w;
  #pragma unroll
  for (int off = 32; off; off >>= 1) ss += __shfl_down(ss, off);
  __shared__ float wsum[4];
  if ((tid & 63) == 0) wsum[tid >> 6] = ss;
  __syncthreads();
  const float tot = wsum[0] + wsum[1] + wsum[2] + wsum[3];
  const float rms = 1.0f / sqrtf(tot * (1.0f / D_) + 1e-6f);
  const float4 gv = ((const float4*)g)[tid];
  float4 o;
  o.x = gv.x * xv.x * rms;
  o.y = gv.y * xv.y * rms;
  o.z = gv.z * xv.z * rms;
  o.w = gv.w * xv.w * rms;
  if (of) ((float4*)(of + (size_t)t * D_))[tid] = o;
  if (ob) {
    ushort4 h;
    h.x = f2bf(o.x); h.y = f2bf(o.y); h.z = f2bf(o.z); h.w = f2bf(o.w);
    ((ushort4*)(ob + (size_t)t * D_))[tid] = h;
  }
  if (ohh) {
    ushort4 hh, hl;
    hh.x = f2h(o.x); hl.x = f2h(o.x - h2f(hh.x));
    hh.y = f2h(o.y); hl.y = f2h(o.y - h2f(hh.y));
    hh.z = f2h(o.z); hl.z = f2h(o.z - h2f(hh.z));
    hh.w = f2h(o.w); hl.w = f2h(o.w - h2f(hh.w));
    ((ushort4*)(ohh + (size_t)t * D_))[tid] = hh;
    ((ushort4*)(ohl + (size_t)t * D_))[tid] = hl;
  }
}

// --------------------------- split-fp16 MFMA GEMM: C = (A)(Bt)^T (+resid) --
template<bool RESID>
__global__ __launch_bounds__(256) void gemm_split(const u16* __restrict__ Ah,
                                                  const u16* __restrict__ Al,
                                                  const u16* __restrict__ Bh,
                                                  const u16* __restrict__ Bl,
                                                  const float* __restrict__ resid,
                                                  float* __restrict__ C,
                                                  int K, int lda, int ldb, int ldc) {
  __shared__ u16 AsH[128 * 32], AsL[128 * 32];
  __shared__ u16 BsH[128 * 32], BsL[128 * 32];
  const int tid = threadIdx.x;
  const int bm = blockIdx.y, bn = blockIdx.x;
  const int lane = tid & 63, wave = tid >> 6;
  const int wy = wave >> 1, wx = wave & 1;
  const int l15 = lane & 15, lq = lane >> 4;
  f32x4 acc[4][4];
  #pragma unroll
  for (int i = 0; i < 4; ++i)
    #pragma unroll
    for (int j = 0; j < 4; ++j)
      #pragma unroll
      for (int r = 0; r < 4; ++r) acc[i][j][r] = 0.0f;
  const int srow = lane >> 2, skc = (lane & 3) * 8;
  size_t ga[2], gb[2];
  int ldsoff[2];
  #pragma unroll
  for (int c = 0; c < 2; ++c) {
    const int q = wave * 2 + c;
    ga[c] = (size_t)(bm * 128 + q * 16 + srow) * lda + skc;
    gb[c] = (size_t)(bn * 128 + q * 16 + srow) * ldb + skc;
    ldsoff[c] = q * 512 + lane * 8;
  }

  for (int kt = 0; kt < K; kt += 32) {
    __syncthreads();
    #pragma unroll
    for (int c = 0; c < 2; ++c) {
      glds16(Ah + ga[c] + kt, &AsH[ldsoff[c]]);
      glds16(Al + ga[c] + kt, &AsL[ldsoff[c]]);
      glds16(Bh + gb[c] + kt, &BsH[ldsoff[c]]);
      glds16(Bl + gb[c] + kt, &BsL[ldsoff[c]]);
    }
    __syncthreads();
    half8 ah[4], al[4], bh[4], bl[4];
    #pragma unroll
    for (int i = 0; i < 4; ++i) {
      const int row = (wy * 64 + i * 16 + l15) * 32 + lq * 8;
      ah[i] = *(const half8*)&AsH[row];
      al[i] = *(const half8*)&AsL[row];
    }
    #pragma unroll
    for (int j = 0; j < 4; ++j) {
      const int row = (wx * 64 + j * 16 + l15) * 32 + lq * 8;
      bh[j] = *(const half8*)&BsH[row];
      bl[j] = *(const half8*)&BsL[row];
    }
    #pragma unroll
    for (int i = 0; i < 4; ++i)
      #pragma unroll
      for (int j = 0; j < 4; ++j) {
        acc[i][j] = __builtin_amdgcn_mfma_f32_16x16x32_f16(ah[i], bh[j], acc[i][j], 0, 0, 0);
        acc[i][j] = __builtin_amdgcn_mfma_f32_16x16x32_f16(ah[i], bl[j], acc[i][j], 0, 0, 0);
        acc[i][j] = __builtin_amdgcn_mfma_f32_16x16x32_f16(al[i], bh[j], acc[i][j], 0, 0, 0);
      }
  }
  #pragma unroll
  for (int i = 0; i < 4; ++i)
    #pragma unroll
    for (int j = 0; j < 4; ++j)
      #pragma unroll
      for (int r = 0; r < 4; ++r) {
        const int row = bm * 128 + wy * 64 + i * 16 + lq * 4 + r;
        const int col = bn * 128 + wx * 64 + j * 16 + l15;
        float v = acc[i][j][r];
        if (RESID) v += resid[(size_t)row * ldc + col];
        C[(size_t)row * ldc + col] = v;
      }
}

// --------------------------- weight transpose + fp16 split -----------------
__global__ __launch_bounds__(256) void wsplit_t_k(const float* __restrict__ src,
                                                  u16* __restrict__ dh,
                                                  u16* __restrict__ dl,
                                                  int R, int C) {
  __shared__ float tile[32][33];
  const int tid = threadIdx.x;
  const int r0 = blockIdx.y * 32, c0 = blockIdx.x * 32;
  const int tx = tid & 31, ty = tid >> 5;
  #pragma unroll
  for (int i = 0; i < 4; ++i)
    tile[ty + i * 8][tx] = src[(size_t)(r0 + ty + i * 8) * C + c0 + tx];
  __syncthreads();
  #pragma unroll
  for (int i = 0; i < 4; ++i) {
    const float v = tile[tx][ty + i * 8];
    const u16 hh = f2h(v);
    const size_t o = (size_t)(c0 + ty + i * 8) * R + r0 + tx;
    dh[o] = hh;
    dl[o] = f2h(v - h2f(hh));
  }
}

// --------------------------- RoPE + split q,k -> bf16 hi/lo ----------------
__global__ __launch_bounds__(256) void ropesplit_k(const float* __restrict__ qkv,
                                                   u16* __restrict__ qhi, u16* __restrict__ qlo,
                                                   u16* __restrict__ khi, u16* __restrict__ klo) {
  const int i = blockIdx.x * 256 + threadIdx.x;   // over T_*H_*32
  const int j = i & 31;
  const int h = (i >> 5) & 15;
  const int t = i >> 9;
  const int s = t & (S_ - 1);
  const int b = t >> 11;
  const int bh = b * 16 + h;
  const float theta = (float)pow(10000.0, -(double)j / 32.0);
  const float fr = (float)s * theta;
  const float c = cosf(fr), sn = sinf(fr);
  const float2 q = *(const float2*)(qkv + (size_t)t * 3072 + h * 64 + 2 * j);
  const float2 k = *(const float2*)(qkv + (size_t)t * 3072 + 1024 + h * 64 + 2 * j);
  const float q0 = (q.x * c - q.y * sn) * 0.125f;
  const float q1 = (q.x * sn + q.y * c) * 0.125f;
  const float k0 = k.x * c - k.y * sn;
  const float k1 = k.x * sn + k.y * c;
  const size_t o = ((size_t)bh * S_ + s) * 32 + j;   // uint (2xu16) index
  const u16 qh0 = f2bf(q0), qh1 = f2bf(q1);
  const u16 kh0 = f2bf(k0), kh1 = f2bf(k1);
  ((unsigned*)qhi)[o] = (unsigned)qh0 | ((unsigned)qh1 << 16);
  ((unsigned*)khi)[o] = (unsigned)kh0 | ((unsigned)kh1 << 16);
  const u16 ql0 = f2bf(q0 - bf2f(qh0)), ql1 = f2bf(q1 - bf2f(qh1));
  const u16 kl0 = f2bf(k0 - bf2f(kh0)), kl1 = f2bf(k1 - bf2f(kh1));
  ((unsigned*)qlo)[o] = (unsigned)ql0 | ((unsigned)ql1 << 16);
  ((unsigned*)klo)[o] = (unsigned)kl0 | ((unsigned)kl1 << 16);
}

// --------------------------- V pack: fp16 hi/lo in K=16 B-operand layout ---
// Per (bh, key-tile kt): group g=(kc*4+n)*64+lane holds 8 u16:
// [ V[kt*64+kc*16+(lane>>4)*4+j][n*16+(lane&15)] hi j=0..3 | lo j=0..3 ]
__global__ __launch_bounds__(256) void vpack_k(const float* __restrict__ qkv,
                                               u16* __restrict__ vpk) {
  const int kt = blockIdx.x, bh = blockIdx.y;
  const int b = bh >> 4, h = bh & 15;
  const int tid = threadIdx.x;
  u16* dst = vpk + (size_t)(bh * 32 + kt) * 8192;
  #pragma unroll
  for (int i = 0; i < 4; ++i) {
    const int g = i * 256 + tid;               // 0..1023
    const int lane = g & 63, n = (g >> 6) & 3, kc = g >> 8;
    const int lq = lane >> 4, l15 = lane & 15;
    const int key = kt * 64 + kc * 16 + lq * 4;
    const int d = n * 16 + l15;
    u16 out[8];
    #pragma unroll
    for (int j = 0; j < 4; ++j) {
      const float v = qkv[(size_t)(b * S_ + key + j) * 3072 + 2048 + h * 64 + d];
      const u16 hh = f2h(v);
      out[j] = hh;
      out[4 + j] = f2h(v - h2f(hh));
    }
    *(ushort8v*)(dst + g * 8) = *(ushort8v*)out;
  }
}

// --------------------------- MFMA flash attention (split-K, chained PV) ----
// S computed transposed: mfma(A=K, B=Q) -> C-layout query=l15, key=lq*4+r,
// which IS the K=16 A-operand layout. PV chains mfma_f32_16x16x16f16 from
// registers (split-fp16 P and V). No P LDS round-trip.
// R7: every qt split into <=8-tile chunks; K LDS XOR-swizzled (no pad) so
// LDS = 32768 B -> 5 blocks/CU. Chunk->(qt,j) map:
//   bi  0..31: qt=24+(bi>>2),      j=bi&3       (heavy first)
//   bi 32..55: qt=16+(bi-32)/3,    j=(bi-32)%3
//   bi 56..71: qt= 8+((bi-56)>>1), j=(bi-56)&1
//   bi 72..79: qt=bi-72,           j=0          (direct write, no combine)
__global__ __launch_bounds__(256, 4) void attn_mfma_k(const u16* __restrict__ qhi,
                                                      const u16* __restrict__ qlo,
                                                      const u16* __restrict__ khi,
                                                      const u16* __restrict__ klo,
                                                      const u16* __restrict__ vpk,
                                                      u16* __restrict__ ahh,
                                                      u16* __restrict__ ahl,
                                                      float* __restrict__ PO,
                                                      float* __restrict__ Pm,
                                                      float* __restrict__ Pl2) {
  __shared__ u16 Kh[64 * 64], Kl[64 * 64];   // [key][dim], XOR-swizzled cols
  __shared__ u16 Vp[8192];                   // packed fp16 hi/lo B-operand
  const int tid = threadIdx.x, lane = tid & 63, wave = tid >> 6;
  const int bi = blockIdx.x;
  int qt, j;
  if (bi < 32)      { qt = 24 + (bi >> 2);        j = bi & 3; }
  else if (bi < 56) { qt = 16 + (bi - 32) / 3;    j = (bi - 32) % 3; }
  else if (bi < 72) { qt = 8 + ((bi - 56) >> 1);  j = (bi - 56) & 1; }
  else              { qt = bi - 72;               j = 0; }
  const int k0 = j * 8;
  const int k1_ = k0 + 8, nk = qt + 1;
  const int k1 = (k1_ < nk) ? k1_ : nk;
  const bool partial = (qt >= 8);
  int slot = 0;
  if (partial)
    slot = (qt < 16) ? (qt - 8) * 2 + j
         : (qt < 24) ? 16 + (qt - 16) * 3 + j
                     : 40 + (qt - 24) * 4 + j;
  const int bh = blockIdx.y;
  const int l15 = lane & 15, lq = lane >> 4;
  const size_t hb = (size_t)bh * S_ * 64;
  // Q as B-operand: lane n=l15 -> query, k=lq*8+j (same per-lane data as A).
  const int qrow = qt * 64 + wave * 16 + l15;
  short8 qh[2], ql[2];
  qh[0] = *(const short8*)(qhi + hb + (size_t)qrow * 64 + lq * 8);
  qh[1] = *(const short8*)(qhi + hb + (size_t)qrow * 64 + 32 + lq * 8);
  ql[0] = *(const short8*)(qlo + hb + (size_t)qrow * 64 + lq * 8);
  ql[1] = *(const short8*)(qlo + hb + (size_t)qrow * 64 + 32 + lq * 8);
  f32x4 O[4];
  #pragma unroll
  for (int n = 0; n < 4; ++n)
    #pragma unroll
    for (int r = 0; r < 4; ++r) O[n][r] = 0.0f;
  float m_i = -__builtin_inff(), l_i = 0.0f;  // for query = wave*16 + l15

  // Per-thread staging addresses (tile-invariant parts).
  const int srow0 = tid >> 3,         sc80 = (tid & 7) * 8;
  const int srow1 = (256 + tid) >> 3, sc81 = sc80;          // rows 32..63
  const int swz0 = srow0 * 64 + (sc80 ^ ((srow0 & 7) << 3));
  const int swz1 = srow1 * 64 + (sc81 ^ ((srow1 & 7) << 3));
  const int vlds = wave * 2048 + lane * 8;
  ushort8v kregH[2], kregL[2], vreg[4];

  // Issue next-tile global loads (stay in flight across compute).
  auto issue_loads = [&](int kt) {
    const size_t koff0 = hb + (size_t)(kt * 64 + srow0) * 64 + sc80;
    const size_t koff1 = hb + (size_t)(kt * 64 + srow1) * 64 + sc81;
    kregH[0] = *(const ushort8v*)(khi + koff0);
    kregL[0] = *(const ushort8v*)(klo + koff0);
    kregH[1] = *(const ushort8v*)(khi + koff1);
    kregL[1] = *(const ushort8v*)(klo + koff1);
    const u16* vg = vpk + (size_t)(bh * 32 + kt) * 8192 + vlds;
    #pragma unroll
    for (int c = 0; c < 4; ++c)
      vreg[c] = *(const ushort8v*)(vg + c * 512);
  };
  // Drain + write staged regs to LDS (swizzled K; lane-linear V).
  auto write_lds = [&]() {
    *(ushort8v*)&Kh[swz0] = kregH[0];
    *(ushort8v*)&Kl[swz0] = kregL[0];
    *(ushort8v*)&Kh[swz1] = kregH[1];
    *(ushort8v*)&Kl[swz1] = kregL[1];
    #pragma unroll
    for (int c = 0; c < 4; ++c)
      *(ushort8v*)&Vp[vlds + c * 512] = vreg[c];
  };

  // Prologue: stage first tile.
  issue_loads(k0);
  write_lds();
  __syncthreads();

  for (int kt = k0; kt < k1; ++kt) {
    const bool pf = (kt + 1 < k1);
    if (pf) issue_loads(kt + 1);   // in flight under compute (T14)
    // ---- S^T = K Q^T (3-product split): sc[kc][r]: key=kc*16+lq*4+r,
    //      query=wave*16+l15 ----
    f32x4 sc[4];
    #pragma unroll
    for (int kc = 0; kc < 4; ++kc)
      #pragma unroll
      for (int r = 0; r < 4; ++r) sc[kc][r] = 0.0f;
    __builtin_amdgcn_s_setprio(1);
    #pragma unroll
    for (int kc = 0; kc < 4; ++kc) {
      const int row = kc * 16 + l15;
      const int x = (row & 7) << 3;
      const short8 kb0 = *(const short8*)&Kh[row * 64 + ((lq * 8) ^ x)];
      const short8 kb1 = *(const short8*)&Kh[row * 64 + ((32 + lq * 8) ^ x)];
      const short8 kl0 = *(const short8*)&Kl[row * 64 + ((lq * 8) ^ x)];
      const short8 kl1 = *(const short8*)&Kl[row * 64 + ((32 + lq * 8) ^ x)];
      sc[kc] = __builtin_amdgcn_mfma_f32_16x16x32_bf16(kb0, qh[0], sc[kc], 0, 0, 0);
      sc[kc] = __builtin_amdgcn_mfma_f32_16x16x32_bf16(kb1, qh[1], sc[kc], 0, 0, 0);
      sc[kc] = __builtin_amdgcn_mfma_f32_16x16x32_bf16(kb0, ql[0], sc[kc], 0, 0, 0);
      sc[kc] = __builtin_amdgcn_mfma_f32_16x16x32_bf16(kb1, ql[1], sc[kc], 0, 0, 0);
      sc[kc] = __builtin_amdgcn_mfma_f32_16x16x32_bf16(kl0, qh[0], sc[kc], 0, 0, 0);
      sc[kc] = __builtin_amdgcn_mfma_f32_16x16x32_bf16(kl1, qh[1], sc[kc], 0, 0, 0);
    }
    __builtin_amdgcn_s_setprio(0);
    // ---- causal mask on the diagonal tile ----
    if (kt == qt) {
      #pragma unroll
      for (int kc = 0; kc < 4; ++kc)
        #pragma unroll
        for (int r = 0; r < 4; ++r)
          if (kc * 16 + lq * 4 + r > wave * 16 + l15) sc[kc][r] = -__builtin_inff();
    }
    // ---- online softmax: row (query) state is per-lane scalar ----
    float mx = -__builtin_inff();
    #pragma unroll
    for (int kc = 0; kc < 4; ++kc)
      #pragma unroll
      for (int r = 0; r < 4; ++r) mx = fmaxf(mx, sc[kc][r]);
    mx = fmaxf(mx, __shfl_xor(mx, 16));
    mx = fmaxf(mx, __shfl_xor(mx, 32));
    const float mn = fmaxf(m_i, mx);
    const float alpha = __expf(m_i - mn);
    m_i = mn;
    f32x4 p[4];
    float rs = 0.0f;
    #pragma unroll
    for (int kc = 0; kc < 4; ++kc)
      #pragma unroll
      for (int r = 0; r < 4; ++r) { p[kc][r] = __expf(sc[kc][r] - m_i); rs += p[kc][r]; }
    rs += __shfl_xor(rs, 16);
    rs += __shfl_xor(rs, 32);
    l_i = l_i * alpha + rs;
    // rescale O: O[n][r] belongs to query lq*4+r -> fetch that query's alpha
    #pragma unroll
    for (int r = 0; r < 4; ++r) {
      const float alr = __shfl(alpha, lq * 4 + r);
      #pragma unroll
      for (int n = 0; n < 4; ++n) O[n][r] *= alr;
    }
    // ---- P -> split-fp16 in registers (K=16 A-operand layout) ----
    half4 ph[4], pl[4];
    #pragma unroll
    for (int kc = 0; kc < 4; ++kc)
      #pragma unroll
      for (int r = 0; r < 4; ++r) {
        const _Float16 hi = (_Float16)p[kc][r];
        ph[kc][r] = hi;
        pl[kc][r] = (_Float16)(p[kc][r] - (float)hi);
      }
    // ---- O += P V, chained K=16 MFMAs (hh, hl, lh) ----
    __builtin_amdgcn_s_setprio(1);
    #pragma unroll
    for (int n = 0; n < 4; ++n)
      #pragma unroll
      for (int kc = 0; kc < 4; ++kc) {
        const int g = ((kc * 4 + n) * 64 + lane) * 8;
        const half4 vh = *(const half4*)&Vp[g];
        const half4 vl = *(const half4*)&Vp[g + 4];
        O[n] = __builtin_amdgcn_mfma_f32_16x16x16f16(ph[kc], vh, O[n], 0, 0, 0);
        O[n] = __builtin_amdgcn_mfma_f32_16x16x16f16(ph[kc], vl, O[n], 0, 0, 0);
        O[n] = __builtin_amdgcn_mfma_f32_16x16x16f16(pl[kc], vh, O[n], 0, 0, 0);
      }
    __builtin_amdgcn_s_setprio(0);
    // All waves done reading tile kt; overwrite LDS with prefetched tile.
    __syncthreads();
    if (pf) write_lds();
    __syncthreads();
  }
  const int b = bh >> 4, h = bh & 15;
  if (!partial) {
    #pragma unroll
    for (int r = 0; r < 4; ++r) {
      const float lr = __shfl(l_i, lq * 4 + r);
      const float inv = 1.0f / lr;
      const int row = qt * 64 + wave * 16 + lq * 4 + r;
      const size_t base = (size_t)(b * S_ + row) * D_ + h * 64 + l15;
      #pragma unroll
      for (int n = 0; n < 4; ++n) {
        const float o = O[n][r] * inv;
        const u16 hh = f2h(o);
        ahh[base + n * 16] = hh;
        ahl[base + n * 16] = f2h(o - h2f(hh));
      }
    }
  } else {
    // unnormalized partials into slot (bh, slot)
    #pragma unroll
    for (int r = 0; r < 4; ++r) {
      const int lr = wave * 16 + lq * 4 + r;
      const size_t idx = ((size_t)bh * NSLOT_ + slot) * 64 + lr;
      float* po = PO + idx * 64;
      #pragma unroll
      for (int n = 0; n < 4; ++n) po[n * 16 + l15] = O[n][r];
    }
    if (lq == 0) {   // lane holds m/l for query wave*16 + l15
      const int lr = wave * 16 + l15;
      const size_t idx = ((size_t)bh * NSLOT_ + slot) * 64 + lr;
      Pm[idx] = m_i; Pl2[idx] = l_i;
    }
  }
}

// --------------------------- combine split-K attention partials ------------
// One block per (qt>=8, bh): merge C(qt) in {2,3,4} chunks for 64 rows x 64 d.
__global__ __launch_bounds__(256) void attn_combine_k(const float* __restrict__ PO,
                                                      const float* __restrict__ Pm,
                                                      const float* __restrict__ Pl2,
                                                      u16* __restrict__ ahh,
                                                      u16* __restrict__ ahl) {
  const int tid = threadIdx.x;
  const int qt = 8 + blockIdx.x;            // 8..31
  const int bh = blockIdx.y, b = bh >> 4, h = bh & 15;
  const int Cq  = (qt < 16) ? 2 : (qt < 24 ? 3 : 4);
  const int off = (qt < 16) ? (qt - 8) * 2
                : (qt < 24) ? 16 + (qt - 16) * 3
                            : 40 + (qt - 24) * 4;
  const int lr = tid >> 2;                  // 0..63 local query row
  const int d0 = (tid & 3) * 16;
  float m[4], w[4];
  float M = -__builtin_inff();
  for (int c = 0; c < Cq; ++c) {
    m[c] = Pm[((size_t)bh * NSLOT_ + off + c) * 64 + lr];
    M = fmaxf(M, m[c]);
  }
  float L = 0.0f;
  for (int c = 0; c < Cq; ++c) {
    w[c] = __expf(m[c] - M);
    L += w[c] * Pl2[((size_t)bh * NSLOT_ + off + c) * 64 + lr];
  }
  const float inv = 1.0f / L;
  const int row = qt * 64 + lr;
  const size_t ob = (size_t)(b * S_ + row) * D_ + h * 64 + d0;
  #pragma unroll
  for (int q4 = 0; q4 < 4; ++q4) {
    float v[4] = {0.0f, 0.0f, 0.0f, 0.0f};
    for (int c = 0; c < Cq; ++c) {
      const float4 o = *(const float4*)(PO +
          (((size_t)bh * NSLOT_ + off + c) * 64 + lr) * 64 + d0 + q4 * 4);
      v[0] = fmaf(w[c], o.x, v[0]);
      v[1] = fmaf(w[c], o.y, v[1]);
      v[2] = fmaf(w[c], o.z, v[2]);
      v[3] = fmaf(w[c], o.w, v[3]);
    }
    ushort4 hh, hl;
    u16* ph = (u16*)&hh;
    u16* pl = (u16*)&hl;
    #pragma unroll
    for (int z = 0; z < 4; ++z) {
      const float vn = v[z] * inv;
      ph[z] = f2h(vn);
      pl[z] = f2h(vn - h2f(ph[z]));
    }
    *(ushort4*)(ahh + ob + q4 * 4) = hh;
    *(ushort4*)(ahl + ob + q4 * 4) = hl;
  }
}

// --------------------------- router: logits + top2 + capacity assign -------
__global__ __launch_bounds__(256) void router_k(const float* __restrict__ y2,
                                                const float* __restrict__ wr,
                                                int*   __restrict__ cnt,
                                                int*   __restrict__ tok_e,
                                                float* __restrict__ tok_g,
                                                int*   __restrict__ tok_p,
                                                int*   __restrict__ etok) {
  const int wave = threadIdx.x >> 6, lane = threadIdx.x & 63;
  const int t = blockIdx.x * 4 + wave;
  const float* xr = y2 + (size_t)t * D_;
  float acc[8];
  #pragma unroll
  for (int e = 0; e < 8; ++e) acc[e] = 0.0f;
  for (int c = 0; c < 16; ++c) {
    const float xv = xr[c * 64 + lane];
    const float* w = wr + (size_t)(c * 64 + lane) * 8;
    #pragma unroll
    for (int e = 0; e < 8; ++e) acc[e] = fmaf(xv, w[e], acc[e]);
  }
  #pragma unroll
  for (int off = 32; off; off >>= 1)
    #pragma unroll
    for (int e = 0; e < 8; ++e) acc[e] += __shfl_down(acc[e], off);
  if (lane == 0) {
    float mx = acc[0];
    #pragma unroll
    for (int e = 1; e < 8; ++e) mx = fmaxf(mx, acc[e]);
    float ex[8], sum = 0.0f;
    #pragma unroll
    for (int e = 0; e < 8; ++e) { ex[e] = expf(acc[e] - mx); sum += ex[e]; }
    int e1 = 0;
    #pragma unroll
    for (int e = 1; e < 8; ++e) if (acc[e] > acc[e1]) e1 = e;
    int e2 = (e1 == 0) ? 1 : 0;
    #pragma unroll
    for (int e = 0; e < 8; ++e) if (e != e1 && acc[e] > acc[e2]) e2 = e;
    const float g1v = ex[e1] / sum, g2v = ex[e2] / sum;
    int p1 = atomicAdd(&cnt[e1], 1);
    int p2 = atomicAdd(&cnt[e2], 1);
    if (p1 < CAP_) etok[e1 * CAP_ + p1] = t; else p1 = -1;
    if (p2 < CAP_) etok[e2 * CAP_ + p2] = t; else p2 = -1;
    tok_e[2*t] = e1;   tok_e[2*t+1] = e2;
    tok_g[2*t] = g1v;  tok_g[2*t+1] = g2v;
    tok_p[2*t] = p1;   tok_p[2*t+1] = p2;
  }
}

// --------------------------- gather tokens per expert (bf16) ---------------
__global__ __launch_bounds__(256) void gather_k(const u16* __restrict__ y2b,
                                                const int* __restrict__ etok,
                                                const int* __restrict__ cnt,
                                                u16* __restrict__ xe) {
  const int e = blockIdx.y, pos = blockIdx.x, tid = threadIdx.x;
  const int n = min(cnt[e], CAP_);
  ushort4* dst = (ushort4*)(xe + (size_t)(e * CAP_ + pos) * D_) + tid;
  if (pos < n) {
    const int t = etok[e * CAP_ + pos];
    *dst = ((const ushort4*)(y2b + (size_t)t * D_))[tid];
  } else {
    *dst = make_ushort4(0, 0, 0, 0);
  }
}

// --------------------------- bf16 MFMA GEMM: C = A * Bt^T ------------------
// R7: T3-min double-buffered — stage tile t+1 before compute of t, one
// barrier per K-step (prefetch DMA drains at the barrier's vmcnt(0)).
template<typename OT, bool RELU>
__global__ __launch_bounds__(256) void gemm_bt(const u16* __restrict__ A,
                                               const u16* __restrict__ Bt,
                                               OT* __restrict__ C,
                                               int M, int N, int K,
                                               int lda, int ldb, int ldc,
                                               long sAz, long sBz, long sCz) {
  __shared__ u16 As[2][128 * 32];
  __shared__ u16 Bs[2][128 * 32];
  const int tid = threadIdx.x;
  A  += (size_t)blockIdx.z * sAz;
  Bt += (size_t)blockIdx.z * sBz;
  C  += (size_t)blockIdx.z * sCz;
  const int bm = blockIdx.y, bn = blockIdx.x;
  const int lane = tid & 63, wave = tid >> 6;
  const int wy = wave >> 1, wx = wave & 1;
  const int l15 = lane & 15, lq = lane >> 4;
  f32x4 acc[4][4];
  #pragma unroll
  for (int i = 0; i < 4; ++i)
    #pragma unroll
    for (int j = 0; j < 4; ++j)
      #pragma unroll
      for (int r = 0; r < 4; ++r) acc[i][j][r] = 0.0f;
  const int srow = lane >> 2, skc = (lane & 3) * 8;
  size_t ga[2], gb[2];
  int ldsoff[2];
  #pragma unroll
  for (int c = 0; c < 2; ++c) {
    const int q = wave * 2 + c;
    ga[c] = (size_t)(bm * 128 + q * 16 + srow) * lda + skc;
    gb[c] = (size_t)(bn * 128 + q * 16 + srow) * ldb + skc;
    ldsoff[c] = q * 512 + lane * 8;
  }
  auto stage = [&](int buf, int kt) {
    #pragma unroll
    for (int c = 0; c < 2; ++c) {
      glds16(A  + ga[c] + kt, &As[buf][ldsoff[c]]);
      glds16(Bt + gb[c] + kt, &Bs[buf][ldsoff[c]]);
    }
  };

  stage(0, 0);
  __syncthreads();          // drains prologue DMA
  int cur = 0;
  for (int kt = 0; kt < K; kt += 32) {
    if (kt + 32 < K) stage(cur ^ 1, kt + 32);   // in flight under compute
    short8 a[4], b[4];
    #pragma unroll
    for (int i = 0; i < 4; ++i)
      a[i] = *(const short8*)&As[cur][(wy * 64 + i * 16 + l15) * 32 + lq * 8];
    #pragma unroll
    for (int j = 0; j < 4; ++j)
      b[j] = *(const short8*)&Bs[cur][(wx * 64 + j * 16 + l15) * 32 + lq * 8];
    #pragma unroll
    for (int i = 0; i < 4; ++i)
      #pragma unroll
      for (int j = 0; j < 4; ++j)
        acc[i][j] = __builtin_amdgcn_mfma_f32_16x16x32_bf16(a[i], b[j], acc[i][j], 0, 0, 0);
    __syncthreads();        // drains next-tile DMA; all reads of cur done
    cur ^= 1;
  }
  #pragma unroll
  for (int i = 0; i < 4; ++i)
    #pragma unroll
    for (int j = 0; j < 4; ++j)
      #pragma unroll
      for (int r = 0; r < 4; ++r) {
        const int row = bm * 128 + wy * 64 + i * 16 + lq * 4 + r;
        const int col = bn * 128 + wx * 64 + j * 16 + l15;
        float v = acc[i][j][r];
        if (RELU) v = fmaxf(v, 0.0f);
        cstore(C + (size_t)row * ldc + col, v);
      }
}

// --------------------------- weight transpose fp32 -> bf16^T ---------------
__global__ __launch_bounds__(256) void transpose_bf_k(const float* __restrict__ src,
                                                      u16* __restrict__ dst,
                                                      int R, int C) {
  __shared__ float tile[32][33];
  const int tid = threadIdx.x;
  const size_t zoff = (size_t)blockIdx.z * R * C;
  const int r0 = blockIdx.y * 32, c0 = blockIdx.x * 32;
  const int tx = tid & 31, ty = tid >> 5;
  #pragma unroll
  for (int i = 0; i < 4; ++i)
    tile[ty + i * 8][tx] = src[zoff + (size_t)(r0 + ty + i * 8) * C + c0 + tx];
  __syncthreads();
  #pragma unroll
  for (int i = 0; i < 4; ++i)
    dst[zoff + (size_t)(c0 + ty + i * 8) * R + r0 + tx] = f2bf(tile[tx][ty + i * 8]);
}

// --------------------------- final combine ---------------------------------
__global__ __launch_bounds__(256) void combine_k(const float* __restrict__ x2,
                                                 const float* __restrict__ ye,
                                                 const int*   __restrict__ tok_e,
                                                 const float* __restrict__ tok_g,
                                                 const int*   __restrict__ tok_p,
                                                 float* __restrict__ out) {
  const int t = blockIdx.x, tid = threadIdx.x;
  float4 v = ((const float4*)(x2 + (size_t)t * D_))[tid];
  #pragma unroll
  for (int r = 0; r < 2; ++r) {
    const int p = tok_p[2 * t + r];
    if (p >= 0) {
      const int e = tok_e[2 * t + r];
      const float g = tok_g[2 * t + r];
      const float4 y = ((const float4*)(ye + (size_t)(e * CAP_ + p) * D_))[tid];
      v.x = fmaf(g, y.x, v.x);
      v.y = fmaf(g, y.y, v.y);
      v.z = fmaf(g, y.z, v.z);
      v.w = fmaf(g, y.w, v.w);
    }
  }
  ((float4*)(out + (size_t)t * D_))[tid] = v;
}

// ---------------------------------------------------------------------------
extern "C" void kernel_launch(void* const* d_in, const int* in_sizes, int n_in,
                              void* d_out, int out_size, void* d_ws, size_t ws_size,
                              hipStream_t stream) {
  const float* x    = (const float*)d_in[0];
  const float* g1   = (const float*)d_in[1];
  const float* wqkv = (const float*)d_in[2];
  const float* wo   = (const float*)d_in[3];
  const float* g2   = (const float*)d_in[4];
  const float* wr   = (const float*)d_in[5];
  const float* w1   = (const float*)d_in[6];
  const float* w2   = (const float*)d_in[7];
  float* out = (float*)d_out;
  char* ws = (char*)d_ws;
  const size_t MB = 1ull << 20;

  // Phase-aliased workspace layout (~233 MB):
  u16*   y1hh  = (u16*)  (ws + 0);          // 8MB  fp16-hi of rmsnorm1 out; reused as qhi
  u16*   y1hl  = (u16*)  (ws + 8 * MB);     // 8MB  fp16-lo; reused as qlo
  u16*   ahh   = (u16*)  (ws + 16 * MB);    // 8MB  attn out fp16-hi
  u16*   ahl   = (u16*)  (ws + 24 * MB);    // 8MB  attn out fp16-lo
  u16*   hbf   = (u16*)  (ws + 0);          // 40MB MoE hidden (aliases the above)
  float* qkv   = (float*)(ws + 40 * MB);    // 48MB, dead after rope/v pack
  float* PO    = (float*)(ws + 40 * MB);    // 37.75MB attn split-K partials (after vpack)
  float* Pm    = (float*)(ws + 78 * MB);    // 0.6MB
  float* Pl2   = (float*)(ws + 79 * MB);    // 0.6MB
  u16*   xe    = (u16*)  (ws + 40 * MB);    // 20MB, aliases qkv/PO (MoE time)
  float* x2    = (float*)(ws + 88 * MB);    // 16MB
  float* y2    = (float*)(ws + 104 * MB);   // 16MB (fp32 for router!)
  u16*   y2b   = (u16*)  (ws + 120 * MB);   // 8MB
  u16*   w1t   = (u16*)  (ws + 128 * MB);   // 32MB  [E][FFN][D] bf16
  u16*   w2t   = (u16*)  (ws + 160 * MB);   // 32MB  [E][D][FFN] bf16
  float* ye    = (float*)(ws + 192 * MB);   // 40MB (MoE time)
  u16*   wqh   = (u16*)  (ws + 192 * MB);   // 6MB  w_qkv^T fp16-hi (dead before rope)
  u16*   wql   = (u16*)  (ws + 198 * MB);   // 6MB  fp16-lo
  u16*   khi   = (u16*)  (ws + 192 * MB);   // 8MB  (after QKV gemm)
  u16*   klo   = (u16*)  (ws + 200 * MB);   // 8MB
  u16*   vpk   = (u16*)  (ws + 208 * MB);   // 16MB packed V fp16 hi/lo
  u16*   woh   = (u16*)  (ws + 224 * MB);   // 2MB  w_o^T fp16-hi (dead before MoE ye)
  u16*   wol   = (u16*)  (ws + 226 * MB);   // 2MB
  int*   cnt   = (int*)  (ws + 232 * MB);
  int*   tok_e = cnt + 16;                  // 2*T
  float* tok_g = (float*)(tok_e + 2 * T_);  // 2*T
  int*   tok_p = (int*)  (tok_g + 2 * T_);  // 2*T
  int*   etok  = tok_p + 2 * T_;            // E*CAP

  init_k<<<1, 64, 0, stream>>>(cnt);
  transpose_bf_k<<<dim3(FFN_/32, D_/32, E_), 256, 0, stream>>>(w1, w1t, D_, FFN_);
  transpose_bf_k<<<dim3(D_/32, FFN_/32, E_), 256, 0, stream>>>(w2, w2t, FFN_, D_);
  // w_qkv (Dx3D) -> [3D][D] fp16 hi/lo; w_o (DxD) -> [D][D] fp16 hi/lo
  wsplit_t_k<<<dim3(3*D_/32, D_/32), 256, 0, stream>>>(wqkv, wqh, wql, D_, 3*D_);
  wsplit_t_k<<<dim3(D_/32, D_/32), 256, 0, stream>>>(wo, woh, wol, D_, D_);

  // x -> rmsnorm -> y1 (fp16 hi/lo only)
  rmsnorm_k<<<T_, 256, 0, stream>>>(x, g1, (float*)nullptr, (u16*)nullptr, y1hh, y1hl);
  // qkv = y1 @ w_qkv via split-fp16 MFMA (fp32 out)
  gemm_split<false><<<dim3(3 * D_ / 128, T_ / 128), 256, 0, stream>>>(
      y1hh, y1hl, wqh, wql, nullptr, qkv, D_, D_, D_, 3 * D_);
  // RoPE + split q,k (q pre-scaled by 1/8); y1hh/y1hl are dead -> reuse as qhi/qlo
  ropesplit_k<<<T_ * H_ * 32 / 256, 256, 0, stream>>>(qkv, y1hh, y1hl, khi, klo);
  // V -> packed fp16 hi/lo B-operand layout
  vpack_k<<<dim3(S_ / 64, B_ * H_), 256, 0, stream>>>(qkv, vpk);
  // MFMA flash attention (balanced split-K, chained PV, T14 pipeline)
  attn_mfma_k<<<dim3(80, B_ * H_), 256, 0, stream>>>(
      y1hh, y1hl, khi, klo, vpk, ahh, ahl, PO, Pm, Pl2);
  attn_combine_k<<<dim3(24, B_ * H_), 256, 0, stream>>>(PO, Pm, Pl2, ahh, ahl);
  // x2 = attn @ w_o + x via split-fp16 MFMA
  gemm_split<true><<<dim3(D_ / 128, T_ / 128), 256, 0, stream>>>(
      ahh, ahl, woh, wol, x, x2, D_, D_, D_, D_);
  // x2 -> rmsnorm -> y2 (fp32) + y2b (bf16)
  rmsnorm_k<<<T_, 256, 0, stream>>>(x2, g2, y2, y2b, (u16*)nullptr, (u16*)nullptr);
  // router (fp32 logits, top-2, capacity assignment)
  router_k<<<T_ / 4, 256, 0, stream>>>(y2, wr, cnt, tok_e, tok_g, tok_p, etok);
  // gather per-expert token rows (bf16)
  gather_k<<<dim3(CAP_, E_), 256, 0, stream>>>(y2b, etok, cnt, xe);
  // h = relu(xe @ w1) (bf16 out), batched over experts
  gemm_bt<u16, true><<<dim3(FFN_/128, CAP_/128, E_), 256, 0, stream>>>(
      xe, w1t, hbf, CAP_, FFN_, D_, D_, D_, FFN_,
      (long)CAP_ * D_, (long)FFN_ * D_, (long)CAP_ * FFN_);
  // ye = h @ w2 (fp32 out)
  gemm_bt<float, false><<<dim3(D_/128, CAP_/128, E_), 256, 0, stream>>>(
      hbf, w2t, ye, CAP_, D_, FFN_, FFN_, FFN_, D_,
      (long)CAP_ * FFN_, (long)D_ * FFN_, (long)CAP_ * D_);
  // out = x2 + sum_r gate_r * ye[...]
  combine_k<<<T_, 256, 0, stream>>>(x2, ye, tok_e, tok_g, tok_p, out);
}

// Round 3
// 644.660 us; speedup vs baseline: 1.1558x; 1.1181x over previous
//
#include <hip/hip_runtime.h>
#include <math.h>

// ---------------------------------------------------------------------------
// Fused transformer block on MI355X.
// Precision: all pre-router math is fp32-equivalent (split-fp16/bf16 MFMA),
// post-routing MoE GEMMs plain bf16 MFMA.
// R5: attention restructured — S computed transposed so P exits QK^T already
// in the K=16 MFMA A-operand layout; PV chains mfma_f32_16x16x16f16 directly
// from registers (no P LDS round-trip).
// R6: T14 async-STAGE staging pipeline + s_setprio around MFMA clusters.
// R7: attention split-K rebalanced (<=8-tile chunks, 2-4-chunk combine);
// K LDS XOR-swizzle (32KB -> 5 blocks/CU); MoE gemm_bt double-buffered.
// R8: router_k hierarchical capacity assignment — 8192 same-cacheline global
// atomics (fully serialized cross-XCD, ~100us) replaced by LDS-atomic local
// ranks + 8 global atomics per 32-token block (1024 total). Slot order within
// an expert changes (order-irrelevant: no overflow at this balance, per-slot
// outputs independent, cnt totals identical).
// ---------------------------------------------------------------------------

#define B_   2
#define S_   2048
#define D_   1024
#define H_   16
#define HD_  64
#define FFN_ 2048
#define E_   8
#define CAP_ 1280
#define T_   (B_*S_)
#define NSLOT_ 72   // partial-chunk slots per (b,h): qt8-15:2ea, 16-23:3ea, 24-31:4ea

typedef unsigned short u16;
typedef __attribute__((ext_vector_type(8))) short     short8;    // MFMA bf16x8 operand
typedef __attribute__((ext_vector_type(8))) _Float16  half8;     // MFMA f16x8 operand
typedef __attribute__((ext_vector_type(4))) _Float16  half4;     // K=16 MFMA f16x4 operand
typedef __attribute__((ext_vector_type(8))) unsigned short ushort8v;
typedef __attribute__((ext_vector_type(4))) float     f32x4;

__device__ __forceinline__ u16 f2bf(float f) {
  unsigned u = __float_as_uint(f);
  return (u16)((u + 0x7fffu + ((u >> 16) & 1u)) >> 16);   // RNE
}
__device__ __forceinline__ float bf2f(u16 h) {
  return __uint_as_float(((unsigned)h) << 16);
}
__device__ __forceinline__ u16 f2h(float f) {
  _Float16 h = (_Float16)f;
  return __builtin_bit_cast(u16, h);
}
__device__ __forceinline__ float h2f(u16 b) {
  return (float)__builtin_bit_cast(_Float16, b);
}

__device__ __forceinline__ void cstore(float* p, float v) { *p = v; }
__device__ __forceinline__ void cstore(u16* p, float v)   { *p = f2bf(v); }

// global -> LDS direct DMA, 16B per lane (lane-linear dest).
__device__ __forceinline__ void glds16(const u16* g, u16* l) {
  __builtin_amdgcn_global_load_lds(
      (const __attribute__((address_space(1))) unsigned int*)g,
      (__attribute__((address_space(3))) unsigned int*)l, 16, 0, 0);
}

// --------------------------- init: zero expert counters --------------------
__global__ void init_k(int* cnt) {
  if (threadIdx.x < 16) cnt[threadIdx.x] = 0;
}

// --------------------------- RMSNorm (fp32 in; fp32/bf16/fp16-split out) ---
__global__ __launch_bounds__(256) void rmsnorm_k(const float* __restrict__ x,
                                                 const float* __restrict__ g,
                                                 float* __restrict__ of,
                                                 u16*   __restrict__ ob,
                                                 u16*   __restrict__ ohh,
                                                 u16*   __restrict__ ohl) {
  const int t = blockIdx.x, tid = threadIdx.x;
  const float4 xv = ((const float4*)(x + (size_t)t * D_))[tid];
  float ss = xv.x*xv.x + xv.y*xv.y + xv.z*xv.z + xv.w*xv.w;
  #pragma unroll
  for (int off = 32; off; off >>= 1) ss += __shfl_down(ss, off);
  __shared__ float wsum[4];
  if ((tid & 63) == 0) wsum[tid >> 6] = ss;
  __syncthreads();
  const float tot = wsum[0] + wsum[1] + wsum[2] + wsum[3];
  const float rms = 1.0f / sqrtf(tot * (1.0f / D_) + 1e-6f);
  const float4 gv = ((const float4*)g)[tid];
  float4 o;
  o.x = gv.x * xv.x * rms;
  o.y = gv.y * xv.y * rms;
  o.z = gv.z * xv.z * rms;
  o.w = gv.w * xv.w * rms;
  if (of) ((float4*)(of + (size_t)t * D_))[tid] = o;
  if (ob) {
    ushort4 h;
    h.x = f2bf(o.x); h.y = f2bf(o.y); h.z = f2bf(o.z); h.w = f2bf(o.w);
    ((ushort4*)(ob + (size_t)t * D_))[tid] = h;
  }
  if (ohh) {
    ushort4 hh, hl;
    hh.x = f2h(o.x); hl.x = f2h(o.x - h2f(hh.x));
    hh.y = f2h(o.y); hl.y = f2h(o.y - h2f(hh.y));
    hh.z = f2h(o.z); hl.z = f2h(o.z - h2f(hh.z));
    hh.w = f2h(o.w); hl.w = f2h(o.w - h2f(hh.w));
    ((ushort4*)(ohh + (size_t)t * D_))[tid] = hh;
    ((ushort4*)(ohl + (size_t)t * D_))[tid] = hl;
  }
}

// --------------------------- split-fp16 MFMA GEMM: C = (A)(Bt)^T (+resid) --
template<bool RESID>
__global__ __launch_bounds__(256) void gemm_split(const u16* __restrict__ Ah,
                                                  const u16* __restrict__ Al,
                                                  const u16* __restrict__ Bh,
                                                  const u16* __restrict__ Bl,
                                                  const float* __restrict__ resid,
                                                  float* __restrict__ C,
                                                  int K, int lda, int ldb, int ldc) {
  __shared__ u16 AsH[128 * 32], AsL[128 * 32];
  __shared__ u16 BsH[128 * 32], BsL[128 * 32];
  const int tid = threadIdx.x;
  const int bm = blockIdx.y, bn = blockIdx.x;
  const int lane = tid & 63, wave = tid >> 6;
  const int wy = wave >> 1, wx = wave & 1;
  const int l15 = lane & 15, lq = lane >> 4;
  f32x4 acc[4][4];
  #pragma unroll
  for (int i = 0; i < 4; ++i)
    #pragma unroll
    for (int j = 0; j < 4; ++j)
      #pragma unroll
      for (int r = 0; r < 4; ++r) acc[i][j][r] = 0.0f;
  const int srow = lane >> 2, skc = (lane & 3) * 8;
  size_t ga[2], gb[2];
  int ldsoff[2];
  #pragma unroll
  for (int c = 0; c < 2; ++c) {
    const int q = wave * 2 + c;
    ga[c] = (size_t)(bm * 128 + q * 16 + srow) * lda + skc;
    gb[c] = (size_t)(bn * 128 + q * 16 + srow) * ldb + skc;
    ldsoff[c] = q * 512 + lane * 8;
  }

  for (int kt = 0; kt < K; kt += 32) {
    __syncthreads();
    #pragma unroll
    for (int c = 0; c < 2; ++c) {
      glds16(Ah + ga[c] + kt, &AsH[ldsoff[c]]);
      glds16(Al + ga[c] + kt, &AsL[ldsoff[c]]);
      glds16(Bh + gb[c] + kt, &BsH[ldsoff[c]]);
      glds16(Bl + gb[c] + kt, &BsL[ldsoff[c]]);
    }
    __syncthreads();
    half8 ah[4], al[4], bh[4], bl[4];
    #pragma unroll
    for (int i = 0; i < 4; ++i) {
      const int row = (wy * 64 + i * 16 + l15) * 32 + lq * 8;
      ah[i] = *(const half8*)&AsH[row];
      al[i] = *(const half8*)&AsL[row];
    }
    #pragma unroll
    for (int j = 0; j < 4; ++j) {
      const int row = (wx * 64 + j * 16 + l15) * 32 + lq * 8;
      bh[j] = *(const half8*)&BsH[row];
      bl[j] = *(const half8*)&BsL[row];
    }
    #pragma unroll
    for (int i = 0; i < 4; ++i)
      #pragma unroll
      for (int j = 0; j < 4; ++j) {
        acc[i][j] = __builtin_amdgcn_mfma_f32_16x16x32_f16(ah[i], bh[j], acc[i][j], 0, 0, 0);
        acc[i][j] = __builtin_amdgcn_mfma_f32_16x16x32_f16(ah[i], bl[j], acc[i][j], 0, 0, 0);
        acc[i][j] = __builtin_amdgcn_mfma_f32_16x16x32_f16(al[i], bh[j], acc[i][j], 0, 0, 0);
      }
  }
  #pragma unroll
  for (int i = 0; i < 4; ++i)
    #pragma unroll
    for (int j = 0; j < 4; ++j)
      #pragma unroll
      for (int r = 0; r < 4; ++r) {
        const int row = bm * 128 + wy * 64 + i * 16 + lq * 4 + r;
        const int col = bn * 128 + wx * 64 + j * 16 + l15;
        float v = acc[i][j][r];
        if (RESID) v += resid[(size_t)row * ldc + col];
        C[(size_t)row * ldc + col] = v;
      }
}

// --------------------------- weight transpose + fp16 split -----------------
__global__ __launch_bounds__(256) void wsplit_t_k(const float* __restrict__ src,
                                                  u16* __restrict__ dh,
                                                  u16* __restrict__ dl,
                                                  int R, int C) {
  __shared__ float tile[32][33];
  const int tid = threadIdx.x;
  const int r0 = blockIdx.y * 32, c0 = blockIdx.x * 32;
  const int tx = tid & 31, ty = tid >> 5;
  #pragma unroll
  for (int i = 0; i < 4; ++i)
    tile[ty + i * 8][tx] = src[(size_t)(r0 + ty + i * 8) * C + c0 + tx];
  __syncthreads();
  #pragma unroll
  for (int i = 0; i < 4; ++i) {
    const float v = tile[tx][ty + i * 8];
    const u16 hh = f2h(v);
    const size_t o = (size_t)(c0 + ty + i * 8) * R + r0 + tx;
    dh[o] = hh;
    dl[o] = f2h(v - h2f(hh));
  }
}

// --------------------------- RoPE + split q,k -> bf16 hi/lo ----------------
__global__ __launch_bounds__(256) void ropesplit_k(const float* __restrict__ qkv,
                                                   u16* __restrict__ qhi, u16* __restrict__ qlo,
                                                   u16* __restrict__ khi, u16* __restrict__ klo) {
  const int i = blockIdx.x * 256 + threadIdx.x;   // over T_*H_*32
  const int j = i & 31;
  const int h = (i >> 5) & 15;
  const int t = i >> 9;
  const int s = t & (S_ - 1);
  const int b = t >> 11;
  const int bh = b * 16 + h;
  const float theta = (float)pow(10000.0, -(double)j / 32.0);
  const float fr = (float)s * theta;
  const float c = cosf(fr), sn = sinf(fr);
  const float2 q = *(const float2*)(qkv + (size_t)t * 3072 + h * 64 + 2 * j);
  const float2 k = *(const float2*)(qkv + (size_t)t * 3072 + 1024 + h * 64 + 2 * j);
  const float q0 = (q.x * c - q.y * sn) * 0.125f;
  const float q1 = (q.x * sn + q.y * c) * 0.125f;
  const float k0 = k.x * c - k.y * sn;
  const float k1 = k.x * sn + k.y * c;
  const size_t o = ((size_t)bh * S_ + s) * 32 + j;   // uint (2xu16) index
  const u16 qh0 = f2bf(q0), qh1 = f2bf(q1);
  const u16 kh0 = f2bf(k0), kh1 = f2bf(k1);
  ((unsigned*)qhi)[o] = (unsigned)qh0 | ((unsigned)qh1 << 16);
  ((unsigned*)khi)[o] = (unsigned)kh0 | ((unsigned)kh1 << 16);
  const u16 ql0 = f2bf(q0 - bf2f(qh0)), ql1 = f2bf(q1 - bf2f(qh1));
  const u16 kl0 = f2bf(k0 - bf2f(kh0)), kl1 = f2bf(k1 - bf2f(kh1));
  ((unsigned*)qlo)[o] = (unsigned)ql0 | ((unsigned)ql1 << 16);
  ((unsigned*)klo)[o] = (unsigned)kl0 | ((unsigned)kl1 << 16);
}

// --------------------------- V pack: fp16 hi/lo in K=16 B-operand layout ---
// Per (bh, key-tile kt): group g=(kc*4+n)*64+lane holds 8 u16:
// [ V[kt*64+kc*16+(lane>>4)*4+j][n*16+(lane&15)] hi j=0..3 | lo j=0..3 ]
__global__ __launch_bounds__(256) void vpack_k(const float* __restrict__ qkv,
                                               u16* __restrict__ vpk) {
  const int kt = blockIdx.x, bh = blockIdx.y;
  const int b = bh >> 4, h = bh & 15;
  const int tid = threadIdx.x;
  u16* dst = vpk + (size_t)(bh * 32 + kt) * 8192;
  #pragma unroll
  for (int i = 0; i < 4; ++i) {
    const int g = i * 256 + tid;               // 0..1023
    const int lane = g & 63, n = (g >> 6) & 3, kc = g >> 8;
    const int lq = lane >> 4, l15 = lane & 15;
    const int key = kt * 64 + kc * 16 + lq * 4;
    const int d = n * 16 + l15;
    u16 out[8];
    #pragma unroll
    for (int j = 0; j < 4; ++j) {
      const float v = qkv[(size_t)(b * S_ + key + j) * 3072 + 2048 + h * 64 + d];
      const u16 hh = f2h(v);
      out[j] = hh;
      out[4 + j] = f2h(v - h2f(hh));
    }
    *(ushort8v*)(dst + g * 8) = *(ushort8v*)out;
  }
}

// --------------------------- MFMA flash attention (split-K, chained PV) ----
// S computed transposed: mfma(A=K, B=Q) -> C-layout query=l15, key=lq*4+r,
// which IS the K=16 A-operand layout. PV chains mfma_f32_16x16x16f16 from
// registers (split-fp16 P and V). No P LDS round-trip.
// R7: every qt split into <=8-tile chunks; K LDS XOR-swizzled (no pad) so
// LDS = 32768 B -> 5 blocks/CU. Chunk->(qt,j) map:
//   bi  0..31: qt=24+(bi>>2),      j=bi&3       (heavy first)
//   bi 32..55: qt=16+(bi-32)/3,    j=(bi-32)%3
//   bi 56..71: qt= 8+((bi-56)>>1), j=(bi-56)&1
//   bi 72..79: qt=bi-72,           j=0          (direct write, no combine)
__global__ __launch_bounds__(256, 4) void attn_mfma_k(const u16* __restrict__ qhi,
                                                      const u16* __restrict__ qlo,
                                                      const u16* __restrict__ khi,
                                                      const u16* __restrict__ klo,
                                                      const u16* __restrict__ vpk,
                                                      u16* __restrict__ ahh,
                                                      u16* __restrict__ ahl,
                                                      float* __restrict__ PO,
                                                      float* __restrict__ Pm,
                                                      float* __restrict__ Pl2) {
  __shared__ u16 Kh[64 * 64], Kl[64 * 64];   // [key][dim], XOR-swizzled cols
  __shared__ u16 Vp[8192];                   // packed fp16 hi/lo B-operand
  const int tid = threadIdx.x, lane = tid & 63, wave = tid >> 6;
  const int bi = blockIdx.x;
  int qt, j;
  if (bi < 32)      { qt = 24 + (bi >> 2);        j = bi & 3; }
  else if (bi < 56) { qt = 16 + (bi - 32) / 3;    j = (bi - 32) % 3; }
  else if (bi < 72) { qt = 8 + ((bi - 56) >> 1);  j = (bi - 56) & 1; }
  else              { qt = bi - 72;               j = 0; }
  const int k0 = j * 8;
  const int k1_ = k0 + 8, nk = qt + 1;
  const int k1 = (k1_ < nk) ? k1_ : nk;
  const bool partial = (qt >= 8);
  int slot = 0;
  if (partial)
    slot = (qt < 16) ? (qt - 8) * 2 + j
         : (qt < 24) ? 16 + (qt - 16) * 3 + j
                     : 40 + (qt - 24) * 4 + j;
  const int bh = blockIdx.y;
  const int l15 = lane & 15, lq = lane >> 4;
  const size_t hb = (size_t)bh * S_ * 64;
  // Q as B-operand: lane n=l15 -> query, k=lq*8+j (same per-lane data as A).
  const int qrow = qt * 64 + wave * 16 + l15;
  short8 qh[2], ql[2];
  qh[0] = *(const short8*)(qhi + hb + (size_t)qrow * 64 + lq * 8);
  qh[1] = *(const short8*)(qhi + hb + (size_t)qrow * 64 + 32 + lq * 8);
  ql[0] = *(const short8*)(qlo + hb + (size_t)qrow * 64 + lq * 8);
  ql[1] = *(const short8*)(qlo + hb + (size_t)qrow * 64 + 32 + lq * 8);
  f32x4 O[4];
  #pragma unroll
  for (int n = 0; n < 4; ++n)
    #pragma unroll
    for (int r = 0; r < 4; ++r) O[n][r] = 0.0f;
  float m_i = -__builtin_inff(), l_i = 0.0f;  // for query = wave*16 + l15

  // Per-thread staging addresses (tile-invariant parts).
  const int srow0 = tid >> 3,         sc80 = (tid & 7) * 8;
  const int srow1 = (256 + tid) >> 3, sc81 = sc80;          // rows 32..63
  const int swz0 = srow0 * 64 + (sc80 ^ ((srow0 & 7) << 3));
  const int swz1 = srow1 * 64 + (sc81 ^ ((srow1 & 7) << 3));
  const int vlds = wave * 2048 + lane * 8;
  ushort8v kregH[2], kregL[2], vreg[4];

  // Issue next-tile global loads (stay in flight across compute).
  auto issue_loads = [&](int kt) {
    const size_t koff0 = hb + (size_t)(kt * 64 + srow0) * 64 + sc80;
    const size_t koff1 = hb + (size_t)(kt * 64 + srow1) * 64 + sc81;
    kregH[0] = *(const ushort8v*)(khi + koff0);
    kregL[0] = *(const ushort8v*)(klo + koff0);
    kregH[1] = *(const ushort8v*)(khi + koff1);
    kregL[1] = *(const ushort8v*)(klo + koff1);
    const u16* vg = vpk + (size_t)(bh * 32 + kt) * 8192 + vlds;
    #pragma unroll
    for (int c = 0; c < 4; ++c)
      vreg[c] = *(const ushort8v*)(vg + c * 512);
  };
  // Drain + write staged regs to LDS (swizzled K; lane-linear V).
  auto write_lds = [&]() {
    *(ushort8v*)&Kh[swz0] = kregH[0];
    *(ushort8v*)&Kl[swz0] = kregL[0];
    *(ushort8v*)&Kh[swz1] = kregH[1];
    *(ushort8v*)&Kl[swz1] = kregL[1];
    #pragma unroll
    for (int c = 0; c < 4; ++c)
      *(ushort8v*)&Vp[vlds + c * 512] = vreg[c];
  };

  // Prologue: stage first tile.
  issue_loads(k0);
  write_lds();
  __syncthreads();

  for (int kt = k0; kt < k1; ++kt) {
    const bool pf = (kt + 1 < k1);
    if (pf) issue_loads(kt + 1);   // in flight under compute (T14)
    // ---- S^T = K Q^T (3-product split): sc[kc][r]: key=kc*16+lq*4+r,
    //      query=wave*16+l15 ----
    f32x4 sc[4];
    #pragma unroll
    for (int kc = 0; kc < 4; ++kc)
      #pragma unroll
      for (int r = 0; r < 4; ++r) sc[kc][r] = 0.0f;
    __builtin_amdgcn_s_setprio(1);
    #pragma unroll
    for (int kc = 0; kc < 4; ++kc) {
      const int row = kc * 16 + l15;
      const int x = (row & 7) << 3;
      const short8 kb0 = *(const short8*)&Kh[row * 64 + ((lq * 8) ^ x)];
      const short8 kb1 = *(const short8*)&Kh[row * 64 + ((32 + lq * 8) ^ x)];
      const short8 kl0 = *(const short8*)&Kl[row * 64 + ((lq * 8) ^ x)];
      const short8 kl1 = *(const short8*)&Kl[row * 64 + ((32 + lq * 8) ^ x)];
      sc[kc] = __builtin_amdgcn_mfma_f32_16x16x32_bf16(kb0, qh[0], sc[kc], 0, 0, 0);
      sc[kc] = __builtin_amdgcn_mfma_f32_16x16x32_bf16(kb1, qh[1], sc[kc], 0, 0, 0);
      sc[kc] = __builtin_amdgcn_mfma_f32_16x16x32_bf16(kb0, ql[0], sc[kc], 0, 0, 0);
      sc[kc] = __builtin_amdgcn_mfma_f32_16x16x32_bf16(kb1, ql[1], sc[kc], 0, 0, 0);
      sc[kc] = __builtin_amdgcn_mfma_f32_16x16x32_bf16(kl0, qh[0], sc[kc], 0, 0, 0);
      sc[kc] = __builtin_amdgcn_mfma_f32_16x16x32_bf16(kl1, qh[1], sc[kc], 0, 0, 0);
    }
    __builtin_amdgcn_s_setprio(0);
    // ---- causal mask on the diagonal tile ----
    if (kt == qt) {
      #pragma unroll
      for (int kc = 0; kc < 4; ++kc)
        #pragma unroll
        for (int r = 0; r < 4; ++r)
          if (kc * 16 + lq * 4 + r > wave * 16 + l15) sc[kc][r] = -__builtin_inff();
    }
    // ---- online softmax: row (query) state is per-lane scalar ----
    float mx = -__builtin_inff();
    #pragma unroll
    for (int kc = 0; kc < 4; ++kc)
      #pragma unroll
      for (int r = 0; r < 4; ++r) mx = fmaxf(mx, sc[kc][r]);
    mx = fmaxf(mx, __shfl_xor(mx, 16));
    mx = fmaxf(mx, __shfl_xor(mx, 32));
    const float mn = fmaxf(m_i, mx);
    const float alpha = __expf(m_i - mn);
    m_i = mn;
    f32x4 p[4];
    float rs = 0.0f;
    #pragma unroll
    for (int kc = 0; kc < 4; ++kc)
      #pragma unroll
      for (int r = 0; r < 4; ++r) { p[kc][r] = __expf(sc[kc][r] - m_i); rs += p[kc][r]; }
    rs += __shfl_xor(rs, 16);
    rs += __shfl_xor(rs, 32);
    l_i = l_i * alpha + rs;
    // rescale O: O[n][r] belongs to query lq*4+r -> fetch that query's alpha
    #pragma unroll
    for (int r = 0; r < 4; ++r) {
      const float alr = __shfl(alpha, lq * 4 + r);
      #pragma unroll
      for (int n = 0; n < 4; ++n) O[n][r] *= alr;
    }
    // ---- P -> split-fp16 in registers (K=16 A-operand layout) ----
    half4 ph[4], pl[4];
    #pragma unroll
    for (int kc = 0; kc < 4; ++kc)
      #pragma unroll
      for (int r = 0; r < 4; ++r) {
        const _Float16 hi = (_Float16)p[kc][r];
        ph[kc][r] = hi;
        pl[kc][r] = (_Float16)(p[kc][r] - (float)hi);
      }
    // ---- O += P V, chained K=16 MFMAs (hh, hl, lh) ----
    __builtin_amdgcn_s_setprio(1);
    #pragma unroll
    for (int n = 0; n < 4; ++n)
      #pragma unroll
      for (int kc = 0; kc < 4; ++kc) {
        const int g = ((kc * 4 + n) * 64 + lane) * 8;
        const half4 vh = *(const half4*)&Vp[g];
        const half4 vl = *(const half4*)&Vp[g + 4];
        O[n] = __builtin_amdgcn_mfma_f32_16x16x16f16(ph[kc], vh, O[n], 0, 0, 0);
        O[n] = __builtin_amdgcn_mfma_f32_16x16x16f16(ph[kc], vl, O[n], 0, 0, 0);
        O[n] = __builtin_amdgcn_mfma_f32_16x16x16f16(pl[kc], vh, O[n], 0, 0, 0);
      }
    __builtin_amdgcn_s_setprio(0);
    // All waves done reading tile kt; overwrite LDS with prefetched tile.
    __syncthreads();
    if (pf) write_lds();
    __syncthreads();
  }
  const int b = bh >> 4, h = bh & 15;
  if (!partial) {
    #pragma unroll
    for (int r = 0; r < 4; ++r) {
      const float lr = __shfl(l_i, lq * 4 + r);
      const float inv = 1.0f / lr;
      const int row = qt * 64 + wave * 16 + lq * 4 + r;
      const size_t base = (size_t)(b * S_ + row) * D_ + h * 64 + l15;
      #pragma unroll
      for (int n = 0; n < 4; ++n) {
        const float o = O[n][r] * inv;
        const u16 hh = f2h(o);
        ahh[base + n * 16] = hh;
        ahl[base + n * 16] = f2h(o - h2f(hh));
      }
    }
  } else {
    // unnormalized partials into slot (bh, slot)
    #pragma unroll
    for (int r = 0; r < 4; ++r) {
      const int lr = wave * 16 + lq * 4 + r;
      const size_t idx = ((size_t)bh * NSLOT_ + slot) * 64 + lr;
      float* po = PO + idx * 64;
      #pragma unroll
      for (int n = 0; n < 4; ++n) po[n * 16 + l15] = O[n][r];
    }
    if (lq == 0) {   // lane holds m/l for query wave*16 + l15
      const int lr = wave * 16 + l15;
      const size_t idx = ((size_t)bh * NSLOT_ + slot) * 64 + lr;
      Pm[idx] = m_i; Pl2[idx] = l_i;
    }
  }
}

// --------------------------- combine split-K attention partials ------------
// One block per (qt>=8, bh): merge C(qt) in {2,3,4} chunks for 64 rows x 64 d.
__global__ __launch_bounds__(256) void attn_combine_k(const float* __restrict__ PO,
                                                      const float* __restrict__ Pm,
                                                      const float* __restrict__ Pl2,
                                                      u16* __restrict__ ahh,
                                                      u16* __restrict__ ahl) {
  const int tid = threadIdx.x;
  const int qt = 8 + blockIdx.x;            // 8..31
  const int bh = blockIdx.y, b = bh >> 4, h = bh & 15;
  const int Cq  = (qt < 16) ? 2 : (qt < 24 ? 3 : 4);
  const int off = (qt < 16) ? (qt - 8) * 2
                : (qt < 24) ? 16 + (qt - 16) * 3
                            : 40 + (qt - 24) * 4;
  const int lr = tid >> 2;                  // 0..63 local query row
  const int d0 = (tid & 3) * 16;
  float m[4], w[4];
  float M = -__builtin_inff();
  for (int c = 0; c < Cq; ++c) {
    m[c] = Pm[((size_t)bh * NSLOT_ + off + c) * 64 + lr];
    M = fmaxf(M, m[c]);
  }
  float L = 0.0f;
  for (int c = 0; c < Cq; ++c) {
    w[c] = __expf(m[c] - M);
    L += w[c] * Pl2[((size_t)bh * NSLOT_ + off + c) * 64 + lr];
  }
  const float inv = 1.0f / L;
  const int row = qt * 64 + lr;
  const size_t ob = (size_t)(b * S_ + row) * D_ + h * 64 + d0;
  #pragma unroll
  for (int q4 = 0; q4 < 4; ++q4) {
    float v[4] = {0.0f, 0.0f, 0.0f, 0.0f};
    for (int c = 0; c < Cq; ++c) {
      const float4 o = *(const float4*)(PO +
          (((size_t)bh * NSLOT_ + off + c) * 64 + lr) * 64 + d0 + q4 * 4);
      v[0] = fmaf(w[c], o.x, v[0]);
      v[1] = fmaf(w[c], o.y, v[1]);
      v[2] = fmaf(w[c], o.z, v[2]);
      v[3] = fmaf(w[c], o.w, v[3]);
    }
    ushort4 hh, hl;
    u16* ph = (u16*)&hh;
    u16* pl = (u16*)&hl;
    #pragma unroll
    for (int z = 0; z < 4; ++z) {
      const float vn = v[z] * inv;
      ph[z] = f2h(vn);
      pl[z] = f2h(vn - h2f(ph[z]));
    }
    *(ushort4*)(ahh + ob + q4 * 4) = hh;
    *(ushort4*)(ahl + ob + q4 * 4) = hl;
  }
}

// --------------------------- router: logits + top2 + capacity assign -------
// R8: hierarchical — per-block (32 tokens) LDS-atomic local ranks, then 8
// global atomics per block reserving contiguous slot ranges per expert.
__global__ __launch_bounds__(256) void router_k(const float* __restrict__ y2,
                                                const float* __restrict__ wr,
                                                int*   __restrict__ cnt,
                                                int*   __restrict__ tok_e,
                                                float* __restrict__ tok_g,
                                                int*   __restrict__ tok_p,
                                                int*   __restrict__ etok) {
  __shared__ int   lcnt[8];    // per-expert count within block
  __shared__ int   base[8];    // global base slot per expert
  __shared__ int   le[64];     // entry -> expert   (entry = 2*localTok + rank)
  __shared__ float lg[64];     // entry -> gate
  __shared__ int   lpo[64];    // entry -> local pos within expert
  const int wave = threadIdx.x >> 6, lane = threadIdx.x & 63;
  const int t0 = blockIdx.x * 32;
  if (threadIdx.x < 8) lcnt[threadIdx.x] = 0;
  __syncthreads();
  for (int i = 0; i < 8; ++i) {
    const int r = wave * 8 + i;            // local token 0..31
    const float* xr = y2 + (size_t)(t0 + r) * D_;
    float acc[8];
    #pragma unroll
    for (int e = 0; e < 8; ++e) acc[e] = 0.0f;
    for (int c = 0; c < 16; ++c) {
      const float xv = xr[c * 64 + lane];
      const float* w = wr + (size_t)(c * 64 + lane) * 8;
      #pragma unroll
      for (int e = 0; e < 8; ++e) acc[e] = fmaf(xv, w[e], acc[e]);
    }
    #pragma unroll
    for (int off = 32; off; off >>= 1)
      #pragma unroll
      for (int e = 0; e < 8; ++e) acc[e] += __shfl_down(acc[e], off);
    if (lane == 0) {
      float mx = acc[0];
      #pragma unroll
      for (int e = 1; e < 8; ++e) mx = fmaxf(mx, acc[e]);
      float ex[8], sum = 0.0f;
      #pragma unroll
      for (int e = 0; e < 8; ++e) { ex[e] = expf(acc[e] - mx); sum += ex[e]; }
      int e1 = 0;
      #pragma unroll
      for (int e = 1; e < 8; ++e) if (acc[e] > acc[e1]) e1 = e;
      int e2 = (e1 == 0) ? 1 : 0;
      #pragma unroll
      for (int e = 0; e < 8; ++e) if (e != e1 && acc[e] > acc[e2]) e2 = e;
      le[2 * r]     = e1;  lg[2 * r]     = ex[e1] / sum;
      le[2 * r + 1] = e2;  lg[2 * r + 1] = ex[e2] / sum;
    }
  }
  __syncthreads();
  if (threadIdx.x < 64) lpo[threadIdx.x] = atomicAdd(&lcnt[le[threadIdx.x]], 1);
  __syncthreads();
  if (threadIdx.x < 8)
    base[threadIdx.x] = atomicAdd(&cnt[threadIdx.x], lcnt[threadIdx.x]);
  __syncthreads();
  if (threadIdx.x < 64) {
    const int t = t0 + (threadIdx.x >> 1);
    const int e = le[threadIdx.x];
    int p = base[e] + lpo[threadIdx.x];
    if (p < CAP_) etok[e * CAP_ + p] = t; else p = -1;
    tok_e[2 * t0 + threadIdx.x] = e;
    tok_g[2 * t0 + threadIdx.x] = lg[threadIdx.x];
    tok_p[2 * t0 + threadIdx.x] = p;
  }
}

// --------------------------- gather tokens per expert (bf16) ---------------
__global__ __launch_bounds__(256) void gather_k(const u16* __restrict__ y2b,
                                                const int* __restrict__ etok,
                                                const int* __restrict__ cnt,
                                                u16* __restrict__ xe) {
  const int e = blockIdx.y, pos = blockIdx.x, tid = threadIdx.x;
  const int n = min(cnt[e], CAP_);
  ushort4* dst = (ushort4*)(xe + (size_t)(e * CAP_ + pos) * D_) + tid;
  if (pos < n) {
    const int t = etok[e * CAP_ + pos];
    *dst = ((const ushort4*)(y2b + (size_t)t * D_))[tid];
  } else {
    *dst = make_ushort4(0, 0, 0, 0);
  }
}

// --------------------------- bf16 MFMA GEMM: C = A * Bt^T ------------------
// R7: T3-min double-buffered — stage tile t+1 before compute of t, one
// barrier per K-step (prefetch DMA drains at the barrier's vmcnt(0)).
template<typename OT, bool RELU>
__global__ __launch_bounds__(256) void gemm_bt(const u16* __restrict__ A,
                                               const u16* __restrict__ Bt,
                                               OT* __restrict__ C,
                                               int M, int N, int K,
                                               int lda, int ldb, int ldc,
                                               long sAz, long sBz, long sCz) {
  __shared__ u16 As[2][128 * 32];
  __shared__ u16 Bs[2][128 * 32];
  const int tid = threadIdx.x;
  A  += (size_t)blockIdx.z * sAz;
  Bt += (size_t)blockIdx.z * sBz;
  C  += (size_t)blockIdx.z * sCz;
  const int bm = blockIdx.y, bn = blockIdx.x;
  const int lane = tid & 63, wave = tid >> 6;
  const int wy = wave >> 1, wx = wave & 1;
  const int l15 = lane & 15, lq = lane >> 4;
  f32x4 acc[4][4];
  #pragma unroll
  for (int i = 0; i < 4; ++i)
    #pragma unroll
    for (int j = 0; j < 4; ++j)
      #pragma unroll
      for (int r = 0; r < 4; ++r) acc[i][j][r] = 0.0f;
  const int srow = lane >> 2, skc = (lane & 3) * 8;
  size_t ga[2], gb[2];
  int ldsoff[2];
  #pragma unroll
  for (int c = 0; c < 2; ++c) {
    const int q = wave * 2 + c;
    ga[c] = (size_t)(bm * 128 + q * 16 + srow) * lda + skc;
    gb[c] = (size_t)(bn * 128 + q * 16 + srow) * ldb + skc;
    ldsoff[c] = q * 512 + lane * 8;
  }
  auto stage = [&](int buf, int kt) {
    #pragma unroll
    for (int c = 0; c < 2; ++c) {
      glds16(A  + ga[c] + kt, &As[buf][ldsoff[c]]);
      glds16(Bt + gb[c] + kt, &Bs[buf][ldsoff[c]]);
    }
  };

  stage(0, 0);
  __syncthreads();          // drains prologue DMA
  int cur = 0;
  for (int kt = 0; kt < K; kt += 32) {
    if (kt + 32 < K) stage(cur ^ 1, kt + 32);   // in flight under compute
    short8 a[4], b[4];
    #pragma unroll
    for (int i = 0; i < 4; ++i)
      a[i] = *(const short8*)&As[cur][(wy * 64 + i * 16 + l15) * 32 + lq * 8];
    #pragma unroll
    for (int j = 0; j < 4; ++j)
      b[j] = *(const short8*)&Bs[cur][(wx * 64 + j * 16 + l15) * 32 + lq * 8];
    #pragma unroll
    for (int i = 0; i < 4; ++i)
      #pragma unroll
      for (int j = 0; j < 4; ++j)
        acc[i][j] = __builtin_amdgcn_mfma_f32_16x16x32_bf16(a[i], b[j], acc[i][j], 0, 0, 0);
    __syncthreads();        // drains next-tile DMA; all reads of cur done
    cur ^= 1;
  }
  #pragma unroll
  for (int i = 0; i < 4; ++i)
    #pragma unroll
    for (int j = 0; j < 4; ++j)
      #pragma unroll
      for (int r = 0; r < 4; ++r) {
        const int row = bm * 128 + wy * 64 + i * 16 + lq * 4 + r;
        const int col = bn * 128 + wx * 64 + j * 16 + l15;
        float v = acc[i][j][r];
        if (RELU) v = fmaxf(v, 0.0f);
        cstore(C + (size_t)row * ldc + col, v);
      }
}

// --------------------------- weight transpose fp32 -> bf16^T ---------------
__global__ __launch_bounds__(256) void transpose_bf_k(const float* __restrict__ src,
                                                      u16* __restrict__ dst,
                                                      int R, int C) {
  __shared__ float tile[32][33];
  const int tid = threadIdx.x;
  const size_t zoff = (size_t)blockIdx.z * R * C;
  const int r0 = blockIdx.y * 32, c0 = blockIdx.x * 32;
  const int tx = tid & 31, ty = tid >> 5;
  #pragma unroll
  for (int i = 0; i < 4; ++i)
    tile[ty + i * 8][tx] = src[zoff + (size_t)(r0 + ty + i * 8) * C + c0 + tx];
  __syncthreads();
  #pragma unroll
  for (int i = 0; i < 4; ++i)
    dst[zoff + (size_t)(c0 + ty + i * 8) * R + r0 + tx] = f2bf(tile[tx][ty + i * 8]);
}

// --------------------------- final combine ---------------------------------
__global__ __launch_bounds__(256) void combine_k(const float* __restrict__ x2,
                                                 const float* __restrict__ ye,
                                                 const int*   __restrict__ tok_e,
                                                 const float* __restrict__ tok_g,
                                                 const int*   __restrict__ tok_p,
                                                 float* __restrict__ out) {
  const int t = blockIdx.x, tid = threadIdx.x;
  float4 v = ((const float4*)(x2 + (size_t)t * D_))[tid];
  #pragma unroll
  for (int r = 0; r < 2; ++r) {
    const int p = tok_p[2 * t + r];
    if (p >= 0) {
      const int e = tok_e[2 * t + r];
      const float g = tok_g[2 * t + r];
      const float4 y = ((const float4*)(ye + (size_t)(e * CAP_ + p) * D_))[tid];
      v.x = fmaf(g, y.x, v.x);
      v.y = fmaf(g, y.y, v.y);
      v.z = fmaf(g, y.z, v.z);
      v.w = fmaf(g, y.w, v.w);
    }
  }
  ((float4*)(out + (size_t)t * D_))[tid] = v;
}

// ---------------------------------------------------------------------------
extern "C" void kernel_launch(void* const* d_in, const int* in_sizes, int n_in,
                              void* d_out, int out_size, void* d_ws, size_t ws_size,
                              hipStream_t stream) {
  const float* x    = (const float*)d_in[0];
  const float* g1   = (const float*)d_in[1];
  const float* wqkv = (const float*)d_in[2];
  const float* wo   = (const float*)d_in[3];
  const float* g2   = (const float*)d_in[4];
  const float* wr   = (const float*)d_in[5];
  const float* w1   = (const float*)d_in[6];
  const float* w2   = (const float*)d_in[7];
  float* out = (float*)d_out;
  char* ws = (char*)d_ws;
  const size_t MB = 1ull << 20;

  // Phase-aliased workspace layout (~233 MB):
  u16*   y1hh  = (u16*)  (ws + 0);          // 8MB  fp16-hi of rmsnorm1 out; reused as qhi
  u16*   y1hl  = (u16*)  (ws + 8 * MB);     // 8MB  fp16-lo; reused as qlo
  u16*   ahh   = (u16*)  (ws + 16 * MB);    // 8MB  attn out fp16-hi
  u16*   ahl   = (u16*)  (ws + 24 * MB);    // 8MB  attn out fp16-lo
  u16*   hbf   = (u16*)  (ws + 0);          // 40MB MoE hidden (aliases the above)
  float* qkv   = (float*)(ws + 40 * MB);    // 48MB, dead after rope/v pack
  float* PO    = (float*)(ws + 40 * MB);    // 37.75MB attn split-K partials (after vpack)
  float* Pm    = (float*)(ws + 78 * MB);    // 0.6MB
  float* Pl2   = (float*)(ws + 79 * MB);    // 0.6MB
  u16*   xe    = (u16*)  (ws + 40 * MB);    // 20MB, aliases qkv/PO (MoE time)
  float* x2    = (float*)(ws + 88 * MB);    // 16MB
  float* y2    = (float*)(ws + 104 * MB);   // 16MB (fp32 for router!)
  u16*   y2b   = (u16*)  (ws + 120 * MB);   // 8MB
  u16*   w1t   = (u16*)  (ws + 128 * MB);   // 32MB  [E][FFN][D] bf16
  u16*   w2t   = (u16*)  (ws + 160 * MB);   // 32MB  [E][D][FFN] bf16
  float* ye    = (float*)(ws + 192 * MB);   // 40MB (MoE time)
  u16*   wqh   = (u16*)  (ws + 192 * MB);   // 6MB  w_qkv^T fp16-hi (dead before rope)
  u16*   wql   = (u16*)  (ws + 198 * MB);   // 6MB  fp16-lo
  u16*   khi   = (u16*)  (ws + 192 * MB);   // 8MB  (after QKV gemm)
  u16*   klo   = (u16*)  (ws + 200 * MB);   // 8MB
  u16*   vpk   = (u16*)  (ws + 208 * MB);   // 16MB packed V fp16 hi/lo
  u16*   woh   = (u16*)  (ws + 224 * MB);   // 2MB  w_o^T fp16-hi (dead before MoE ye)
  u16*   wol   = (u16*)  (ws + 226 * MB);   // 2MB
  int*   cnt   = (int*)  (ws + 232 * MB);
  int*   tok_e = cnt + 16;                  // 2*T
  float* tok_g = (float*)(tok_e + 2 * T_);  // 2*T
  int*   tok_p = (int*)  (tok_g + 2 * T_);  // 2*T
  int*   etok  = tok_p + 2 * T_;            // E*CAP

  init_k<<<1, 64, 0, stream>>>(cnt);
  transpose_bf_k<<<dim3(FFN_/32, D_/32, E_), 256, 0, stream>>>(w1, w1t, D_, FFN_);
  transpose_bf_k<<<dim3(D_/32, FFN_/32, E_), 256, 0, stream>>>(w2, w2t, FFN_, D_);
  // w_qkv (Dx3D) -> [3D][D] fp16 hi/lo; w_o (DxD) -> [D][D] fp16 hi/lo
  wsplit_t_k<<<dim3(3*D_/32, D_/32), 256, 0, stream>>>(wqkv, wqh, wql, D_, 3*D_);
  wsplit_t_k<<<dim3(D_/32, D_/32), 256, 0, stream>>>(wo, woh, wol, D_, D_);

  // x -> rmsnorm -> y1 (fp16 hi/lo only)
  rmsnorm_k<<<T_, 256, 0, stream>>>(x, g1, (float*)nullptr, (u16*)nullptr, y1hh, y1hl);
  // qkv = y1 @ w_qkv via split-fp16 MFMA (fp32 out)
  gemm_split<false><<<dim3(3 * D_ / 128, T_ / 128), 256, 0, stream>>>(
      y1hh, y1hl, wqh, wql, nullptr, qkv, D_, D_, D_, 3 * D_);
  // RoPE + split q,k (q pre-scaled by 1/8); y1hh/y1hl are dead -> reuse as qhi/qlo
  ropesplit_k<<<T_ * H_ * 32 / 256, 256, 0, stream>>>(qkv, y1hh, y1hl, khi, klo);
  // V -> packed fp16 hi/lo B-operand layout
  vpack_k<<<dim3(S_ / 64, B_ * H_), 256, 0, stream>>>(qkv, vpk);
  // MFMA flash attention (balanced split-K, chained PV, T14 pipeline)
  attn_mfma_k<<<dim3(80, B_ * H_), 256, 0, stream>>>(
      y1hh, y1hl, khi, klo, vpk, ahh, ahl, PO, Pm, Pl2);
  attn_combine_k<<<dim3(24, B_ * H_), 256, 0, stream>>>(PO, Pm, Pl2, ahh, ahl);
  // x2 = attn @ w_o + x via split-fp16 MFMA
  gemm_split<true><<<dim3(D_ / 128, T_ / 128), 256, 0, stream>>>(
      ahh, ahl, woh, wol, x, x2, D_, D_, D_, D_);
  // x2 -> rmsnorm -> y2 (fp32) + y2b (bf16)
  rmsnorm_k<<<T_, 256, 0, stream>>>(x2, g2, y2, y2b, (u16*)nullptr, (u16*)nullptr);
  // router (hierarchical capacity assignment, 32 tokens/block)
  router_k<<<T_ / 32, 256, 0, stream>>>(y2, wr, cnt, tok_e, tok_g, tok_p, etok);
  // gather per-expert token rows (bf16)
  gather_k<<<dim3(CAP_, E_), 256, 0, stream>>>(y2b, etok, cnt, xe);
  // h = relu(xe @ w1) (bf16 out), batched over experts
  gemm_bt<u16, true><<<dim3(FFN_/128, CAP_/128, E_), 256, 0, stream>>>(
      xe, w1t, hbf, CAP_, FFN_, D_, D_, D_, FFN_,
      (long)CAP_ * D_, (long)FFN_ * D_, (long)CAP_ * FFN_);
  // ye = h @ w2 (fp32 out)
  gemm_bt<float, false><<<dim3(D_/128, CAP_/128, E_), 256, 0, stream>>>(
      hbf, w2t, ye, CAP_, D_, FFN_, FFN_, FFN_, D_,
      (long)CAP_ * FFN_, (long)D_ * FFN_, (long)CAP_ * D_);
  // out = x2 + sum_r gate_r * ye[...]
  combine_k<<<T_, 256, 0, stream>>>(x2, ye, tok_e, tok_g, tok_p, out);
}